// Round 14
// baseline (7269.978 us; speedup 1.0000x reference)
//
#include <hip/hip_runtime.h>
#include <stdint.h>

#define DM 512
#define DH 64

typedef __bf16 bf16x8 __attribute__((ext_vector_type(8)));
typedef float f32x4 __attribute__((ext_vector_type(4)));

__device__ __forceinline__ float bf2f(unsigned short h) {
  union { unsigned int u; float f; } c; c.u = ((unsigned int)h) << 16; return c.f;
}
__device__ __forceinline__ unsigned short f2bf(float f) {
  union { float f; unsigned int u; } c; c.f = f;
  unsigned int u = c.u;
  return (unsigned short)((u + 0x7FFFu + ((u >> 16) & 1u)) >> 16);
}
__device__ __forceinline__ void unpack8(uint4 v, float* f) {
  f[0] = bf2f((unsigned short)(v.x & 0xffff)); f[1] = bf2f((unsigned short)(v.x >> 16));
  f[2] = bf2f((unsigned short)(v.y & 0xffff)); f[3] = bf2f((unsigned short)(v.y >> 16));
  f[4] = bf2f((unsigned short)(v.z & 0xffff)); f[5] = bf2f((unsigned short)(v.z >> 16));
  f[6] = bf2f((unsigned short)(v.w & 0xffff)); f[7] = bf2f((unsigned short)(v.w >> 16));
}
__device__ __forceinline__ float dot8(uint4 kv, const float* qf) {
  float s;
  s  = bf2f((unsigned short)(kv.x & 0xffff)) * qf[0];
  s += bf2f((unsigned short)(kv.x >> 16))    * qf[1];
  s += bf2f((unsigned short)(kv.y & 0xffff)) * qf[2];
  s += bf2f((unsigned short)(kv.y >> 16))    * qf[3];
  s += bf2f((unsigned short)(kv.z & 0xffff)) * qf[4];
  s += bf2f((unsigned short)(kv.z >> 16))    * qf[5];
  s += bf2f((unsigned short)(kv.w & 0xffff)) * qf[6];
  s += bf2f((unsigned short)(kv.w >> 16))    * qf[7];
  return s;
}

// ---------------- Threefry-2x32 (20 rounds), JAX-compatible ----------------
__host__ __device__ inline void tf2x32(uint32_t k0, uint32_t k1, uint32_t x0, uint32_t x1,
                                       uint32_t* o0, uint32_t* o1) {
  uint32_t ks2 = k0 ^ k1 ^ 0x1BD11BDAu;
#define TFR(r) { x0 += x1; x1 = (x1 << r) | (x1 >> (32 - r)); x1 ^= x0; }
  x0 += k0; x1 += k1;
  TFR(13) TFR(15) TFR(26) TFR(6)
  x0 += k1; x1 += ks2 + 1u;
  TFR(17) TFR(29) TFR(16) TFR(24)
  x0 += ks2; x1 += k0 + 2u;
  TFR(13) TFR(15) TFR(26) TFR(6)
  x0 += k0; x1 += k1 + 3u;
  TFR(17) TFR(29) TFR(16) TFR(24)
  x0 += k1; x1 += ks2 + 4u;
  TFR(13) TFR(15) TFR(26) TFR(6)
  *o0 = x0 + ks2; *o1 = x1 + k0 + 5u;
#undef TFR
}

__global__ void idx_kernel(int* __restrict__ idx, int nhalf, unsigned int k0, unsigned int k1, int mask) {
  int m = blockIdx.x * 256 + threadIdx.x;
  if (m >= nhalf) return;
  uint32_t o0, o1;
  tf2x32(k0, k1, (uint32_t)m, (uint32_t)(m + nhalf), &o0, &o1);
  idx[m] = (int)(o0 & (uint32_t)mask);
  idx[m + nhalf] = (int)(o1 & (uint32_t)mask);
}

// ---------------- bf16 GEMM: C(M,N) = A(M,K) * B(N,K)^T + bias -------------
// 1D grid, XCD-bijective swizzle; bn = wgid % NBN (fast), bm = wgid / NBN.
// BK=64 (8 K-iters at K=512); XOR-swizzled LDS via pre-swizzled global src.
// Epilogue: C tile repacked through LDS (32x128 bf16 slice per i, stride 136)
// -> coalesced 16B stores, 2 chunks per thread (32x128 = 4096 elems =
// 256 thr x 2 x 8). Fixes 2x HBM write amplification; values bit-identical.
// EPI: 1 = bf16; 2 = gelu->bf16; 3 = bf16 QKV-split (col>>9 selects Q/K/V).
// CIRC: logical A row m, col k -> A[b*L + ((l-1+t) mod L)][k%512], t=k/512.
__device__ __forceinline__ void async_copy16(void* lds, const void* g) {
  __builtin_amdgcn_global_load_lds((const __attribute__((address_space(1))) unsigned int*)g,
                                   (__attribute__((address_space(3))) unsigned int*)lds,
                                   16, 0, 0);
}

template<int EPI, int CIRC>
__global__ __launch_bounds__(256) void gemm_bt(
    const unsigned short* __restrict__ A, const unsigned short* __restrict__ Bw,
    const float* __restrict__ bias, unsigned short* __restrict__ Cb,
    int M, int N, int K, int L, int Lsh, size_t qkvs, int NBN, int xswz)
{
  __shared__ unsigned short sA[128 * 64];
  __shared__ unsigned short sB[128 * 64];
  const int tid = threadIdx.x;
  const int wave = tid >> 6, lane = tid & 63;

  int blk = blockIdx.x;
  if (xswz) { int cpx = (int)gridDim.x >> 3; blk = (blk & 7) * cpx + (blk >> 3); }
  const int bn = blk % NBN, bm = blk / NBN;

  const int wm = (wave >> 1) << 6, wn = (wave & 1) << 6;

  const int srow = (wave << 5) + (lane >> 3);
  const int kb = (((lane & 7) ^ ((lane >> 3) & 7)) << 3);

  const unsigned short* gA = nullptr;
  int lI = 0;
  if constexpr (CIRC) {
    int r = bm * 128 + srow;
    lI = r & (L - 1);
  } else {
    gA = A + (size_t)(bm * 128 + srow) * K + kb;
  }
  const unsigned short* gB = Bw + (size_t)(bn * 128 + srow) * K + kb;

  f32x4 acc[4][4] = {};

  for (int k0 = 0; k0 < K; k0 += 64) {
#pragma unroll
    for (int q = 0; q < 4; q++) {
      unsigned short* ldsA = &sA[((wave << 5) + (q << 3)) << 6];
      unsigned short* ldsB = &sB[((wave << 5) + (q << 3)) << 6];
      if constexpr (CIRC) {
        int t = k0 >> 9;
        int kk = (k0 & 511) + kb;
        int sl = (lI + (q << 3) - 1 + t + L) & (L - 1);
        int bq = (bm * 128 + srow + (q << 3)) >> Lsh;
        async_copy16(ldsA, A + (((size_t)(bq * L + sl)) << 9) + kk);
      } else {
        async_copy16(ldsA, gA + (size_t)(q << 3) * K + k0);
      }
      async_copy16(ldsB, gB + (size_t)(q << 3) * K + k0);
    }
    __syncthreads();
#pragma unroll
    for (int kk = 0; kk < 2; kk++) {
      bf16x8 af[4], bfr[4];
#pragma unroll
      for (int i = 0; i < 4; i++) {
        int row = wm + (i << 4) + (lane & 15);
        int slot = ((kk << 2) + (lane >> 4)) ^ (lane & 7);
        af[i] = *(const bf16x8*)&sA[(row << 6) + (slot << 3)];
      }
#pragma unroll
      for (int j = 0; j < 4; j++) {
        int row = wn + (j << 4) + (lane & 15);
        int slot = ((kk << 2) + (lane >> 4)) ^ (lane & 7);
        bfr[j] = *(const bf16x8*)&sB[(row << 6) + (slot << 3)];
      }
#pragma unroll
      for (int i = 0; i < 4; i++)
#pragma unroll
        for (int j = 0; j < 4; j++)
          acc[i][j] = __builtin_amdgcn_mfma_f32_16x16x32_bf16(af[i], bfr[j], acc[i][j], 0, 0, 0);
    }
    __syncthreads();
  }

  // ---- epilogue: LDS repack, coalesced stores (2 chunks/thread) ----
  unsigned short* sOut = sA;                 // 32 rows x stride 136
  const int cr = (lane >> 4) << 2;
  const int cc = lane & 15;
  const int lrb = ((wave >> 1) << 4) + cr;   // local row base (+r)
#pragma unroll 1
  for (int i = 0; i < 4; i++) {
    if (i) __syncthreads();
#pragma unroll
    for (int j = 0; j < 4; j++) {
      const int col = wn + (j << 4) + cc;
      const float bvv = bias[(bn << 7) + col];
#pragma unroll
      for (int r = 0; r < 4; r++) {
        float v = acc[i][j][r] + bvv;
        if constexpr (EPI == 2) {
          v = 0.5f * v * (1.0f + erff(v * 0.70710678118654752f));
        }
        sOut[(lrb + r) * 136 + col] = f2bf(v);
      }
    }
    __syncthreads();
    int lr = tid >> 3, ch0 = tid & 7;
    int grow = (bm << 7) + ((lr >> 4) << 6) + (i << 4) + (lr & 15);
#pragma unroll
    for (int cpart = 0; cpart < 2; cpart++) {
      int ch = ch0 + (cpart << 3);
      uint4 val = *(const uint4*)&sOut[lr * 136 + (ch << 3)];
      if constexpr (EPI == 3) {
        int gcol = (bn << 7) + (ch << 3);
        *(uint4*)&Cb[(size_t)(gcol >> 9) * qkvs + ((size_t)grow << 9) + (gcol & 511)] = val;
      } else {
        *(uint4*)&Cb[(size_t)grow * N + (bn << 7) + (ch << 3)] = val;
      }
    }
  }
}

// ---------------- embedding circular conv (C=7, W=3) -> bf16 ---------------
__global__ __launch_bounds__(256) void embed_kernel(const float* __restrict__ xe,
    const float* __restrict__ w, unsigned short* __restrict__ xb)
{
  int blk = blockIdx.x;             // nb * 64
  int b = blk >> 6, lg = blk & 63;
  int l0 = lg << 5;
  int tid = threadIdx.x;
  __shared__ float xwin[34 * 7];
  for (int i = tid; i < 34 * 7; i += 256) {
    int r = i / 7, c = i - r * 7;
    int sl = (l0 - 1 + r) & 2047;
    xwin[i] = xe[((size_t)(b * 2048 + sl)) * 7 + c];
  }
  __syncthreads();
  float wr0[21], wr1[21];
  const float* w0 = w + tid * 21;
  const float* w1 = w + (tid + 256) * 21;
#pragma unroll
  for (int k = 0; k < 21; k++) { wr0[k] = w0[k]; wr1[k] = w1[k]; }
#pragma unroll 1
  for (int ll = 0; ll < 32; ll++) {
    float a0 = 0.0f, a1 = 0.0f;
#pragma unroll
    for (int c = 0; c < 7; c++)
#pragma unroll
      for (int t = 0; t < 3; t++) {
        float xv = xwin[(ll + t) * 7 + c];
        a0 += xv * wr0[c * 3 + t];
        a1 += xv * wr1[c * 3 + t];
      }
    size_t o = ((size_t)(b * 2048 + l0 + ll)) << 9;
    xb[o + tid] = f2bf(a0);
    xb[o + 256 + tid] = f2bf(a1);
  }
}

// ---------------- M = max_j(qk_samp) - sum_j(qk_samp)/L --------------------
template<int U>
__global__ __launch_bounds__(256) void msamp_kernel(
    const unsigned short* __restrict__ qb, const unsigned short* __restrict__ kbuf,
    const int* __restrict__ idx, float* __restrict__ Mv, int L, int nlc, float invL,
    int xcdgrp)
{
  const int RB = 16;
  int blk = blockIdx.x;
  int b, lc;
  if (xcdgrp) {
    int xcd = blk & 7, slot = blk >> 3;
    int g = slot / nlc; lc = slot - g * nlc;
    b = g * 8 + xcd;
  } else {
    b = blk / nlc; lc = blk - b * nlc;
  }
  int l0 = lc * RB;
  int tid = threadIdx.x;
  int wave = tid >> 6, lane = tid & 63;
  int p = lane & 7, h = lane >> 3;
  __shared__ int iidx[RB * U];
  __shared__ float pM[RB * 8 * 25];

  for (int i = tid; i < RB * U; i += 256) iidx[i] = idx[l0 * U + i];
  __syncthreads();

  const size_t rowbase = ((size_t)(b * L)) << 9;
#pragma unroll
  for (int r = 0; r < RB / 4; r++) {
    int l = wave * (RB / 4) + r;
    uint4 qv = *(const uint4*)(qb + rowbase + (((size_t)(l0 + l)) << 9) + (lane << 3));
    float qf[8]; unpack8(qv, qf);
    int kr[U];
#pragma unroll
    for (int j = 0; j < U; j++) kr[j] = iidx[l * U + j];
#pragma unroll
    for (int j = 0; j < U; j++) {
      uint4 kv = *(const uint4*)(kbuf + rowbase + (((size_t)kr[j]) << 9) + (lane << 3));
      float s = dot8(kv, qf);
      s += __shfl_xor(s, 1);
      s += __shfl_xor(s, 2);
      s += __shfl_xor(s, 4);
      if (p == 0) pM[(l * 8 + h) * 25 + j] = s;
    }
  }
  __syncthreads();

  if (tid < RB * 8) {
    int l = tid >> 3, hh = tid & 7;
    float mx = -3.0e38f, sm = 0.0f;
    const float* pr = &pM[tid * 25];
    for (int j = 0; j < U; j++) { float v = pr[j]; mx = fmaxf(mx, v); sm += v; }
    Mv[((size_t)((b << 3) + hh)) * L + l0 + l] = mx - sm * invL;
  }
}

// ---------------- top-u: register-resident, shuffle-reduce -----------------
template<int S>
__global__ __launch_bounds__(256) void topk_kernel(const float* __restrict__ Mv,
    int* __restrict__ mtop, int L, int u)
{
  int bh = blockIdx.x; int tid = threadIdx.x;
  int wave = tid >> 6, lane = tid & 63;
  float lv[S];
#pragma unroll
  for (int s = 0; s < S; s++) lv[s] = Mv[(size_t)bh * L + s * 256 + tid];
  __shared__ float sv[4];
  __shared__ int si[4];
  for (int t = 0; t < u; t++) {
    float bv = lv[0]; int bs = 0;
#pragma unroll
    for (int s = 1; s < S; s++) if (lv[s] > bv) { bv = lv[s]; bs = s; }
    int bi = bs * 256 + tid;
#pragma unroll
    for (int o = 1; o < 64; o <<= 1) {
      float ov = __shfl_xor(bv, o); int oi = __shfl_xor(bi, o);
      if (ov > bv || (ov == bv && oi < bi)) { bv = ov; bi = oi; }
    }
    if (lane == 0) { sv[wave] = bv; si[wave] = bi; }
    __syncthreads();
    float wv = sv[0]; int wi = si[0];
#pragma unroll
    for (int w = 1; w < 4; w++) {
      float ov = sv[w]; int oi = si[w];
      if (ov > wv || (ov == wv && oi < wi)) { wv = ov; wi = oi; }
    }
    if (tid == 0) mtop[bh * u + t] = wi;
#pragma unroll
    for (int s = 0; s < S; s++)
      if (s == (wi >> 8) && (wi & 255) == tid) lv[s] = -3.0e38f;
    __syncthreads();
  }
}

// ---------------- attention part: one 256-row K/V chunk per block ----------
template<int U>
__device__ __forceinline__ void dot_rows(const unsigned short* __restrict__ krow,
                                         const float* __restrict__ qred, float* s)
{
#pragma unroll
  for (int j = 0; j < U; j++) s[j] = 0.0f;
  const uint4* kv4 = (const uint4*)krow;
#pragma unroll
  for (int d8 = 0; d8 < 8; d8++) {
    uint4 kv = kv4[d8];
    float kf[8];
    kf[0] = bf2f((unsigned short)(kv.x & 0xffff)); kf[1] = bf2f((unsigned short)(kv.x >> 16));
    kf[2] = bf2f((unsigned short)(kv.y & 0xffff)); kf[3] = bf2f((unsigned short)(kv.y >> 16));
    kf[4] = bf2f((unsigned short)(kv.z & 0xffff)); kf[5] = bf2f((unsigned short)(kv.z >> 16));
    kf[6] = bf2f((unsigned short)(kv.w & 0xffff)); kf[7] = bf2f((unsigned short)(kv.w >> 16));
#pragma unroll
    for (int j = 0; j < U; j++) {
      const float4 q0 = *(const float4*)&qred[j * 64 + d8 * 8];
      const float4 q1 = *(const float4*)&qred[j * 64 + d8 * 8 + 4];
      s[j] += kf[0] * q0.x + kf[1] * q0.y + kf[2] * q0.z + kf[3] * q0.w
            + kf[4] * q1.x + kf[5] * q1.y + kf[6] * q1.z + kf[7] * q1.w;
    }
  }
}

template<int U>
__global__ __launch_bounds__(256) void attn_part(
    const unsigned short* __restrict__ qb, const unsigned short* __restrict__ kbuf,
    const unsigned short* __restrict__ vbuf, const int* __restrict__ mtop,
    float* __restrict__ pupd, float* __restrict__ pden, float* __restrict__ pvs,
    int L, int S)
{
  int blk = blockIdx.x;
  int bh = blk / S, split = blk - bh * S;
  int b = bh >> 3, h = bh & 7;
  int tid = threadIdx.x;
  __shared__ float qred[U * 64];
  __shared__ float pA[U * 4 * 66];
  __shared__ float pB[U * 256];
  __shared__ float pC[256];
  __shared__ float dnred[4 * U];

  for (int i = tid; i < U * 64; i += 256) {
    int j = i >> 6, d = i & 63;
    int row = mtop[bh * U + j];
    qred[i] = bf2f(qb[(((size_t)(b * L + row)) << 9) + h * 64 + d]) * 0.125f;
  }
  __syncthreads();

  int l = (split << 8) + tid;
  {
    float s[U];
    dot_rows<U>(kbuf + (((size_t)(b * L + l)) << 9) + h * 64, qred, s);
    int g0 = tid >> 6, d0 = tid & 63;
#pragma unroll
    for (int j = 0; j < U; j++) pA[(j * 4 + g0) * 66 + d0] = expf(s[j]);
  }
  __syncthreads();

  int g = tid >> 6, d = tid & 63;
  const unsigned short* vcol = vbuf + (((size_t)(b * L)) << 9) + h * 64 + d;
  float lupd[U], ldn[U]; float lvs = 0.0f;
#pragma unroll
  for (int j = 0; j < U; j++) { lupd[j] = 0.0f; ldn[j] = 0.0f; }
#pragma unroll 1
  for (int li = 0; li < 64; li++) {
    int ll = (split << 8) + (g << 6) + li;
    float vd = bf2f(vcol[(size_t)ll << 9]);
    lvs += vd;
#pragma unroll
    for (int j = 0; j < U; j++) {
      float pv = pA[(j * 4 + g) * 66 + li];
      ldn[j] += pv; lupd[j] += pv * vd;
    }
  }
  if (d == 0) {
#pragma unroll
    for (int j = 0; j < U; j++) dnred[g * U + j] = ldn[j];
  }
#pragma unroll
  for (int j = 0; j < U; j++) pB[(g * U + j) * 64 + d] = lupd[j];
  pC[tid] = lvs;
  __syncthreads();

  size_t base = (size_t)bh * S + split;
  for (int i = tid; i < U * 64; i += 256) {
    int j = i >> 6, dd = i & 63;
    pupd[base * (U * 64) + i] = pB[j * 64 + dd] + pB[(U + j) * 64 + dd]
                              + pB[(2 * U + j) * 64 + dd] + pB[(3 * U + j) * 64 + dd];
  }
  if (tid < U)
    pden[base * U + tid] = dnred[tid] + dnred[U + tid] + dnred[2 * U + tid] + dnred[3 * U + tid];
  if (tid < 64)
    pvs[base * 64 + tid] = pC[tid] + pC[64 + tid] + pC[128 + tid] + pC[192 + tid];
}

// ---------------- attention combine: vmean bcast + top-row scatter ---------
template<int U>
__global__ __launch_bounds__(256) void attn_comb(
    const int* __restrict__ mtop, const float* __restrict__ pupd,
    const float* __restrict__ pden, const float* __restrict__ pvs,
    unsigned short* __restrict__ ab, int L, int S)
{
  int bh = blockIdx.x; int b = bh >> 3, h = bh & 7;
  int tid = threadIdx.x;
  __shared__ float updf[U * 64];
  __shared__ float den[U];
  __shared__ float vm[64];
  for (int i = tid; i < U * 64; i += 256) {
    float s = 0.0f;
    for (int sp = 0; sp < S; sp++) s += pupd[((size_t)bh * S + sp) * (U * 64) + i];
    updf[i] = s;
  }
  if (tid < U) {
    float s = 0.0f;
    for (int sp = 0; sp < S; sp++) s += pden[((size_t)bh * S + sp) * U + tid];
    den[tid] = s;
  }
  if (tid < 64) {
    float s = 0.0f;
    for (int sp = 0; sp < S; sp++) s += pvs[((size_t)bh * S + sp) * 64 + tid];
    vm[tid] = s / (float)L;
  }
  __syncthreads();
  int g = tid >> 6, d = tid & 63;
  unsigned short vmb = f2bf(vm[d]);
  for (int l = g; l < L; l += 4)
    ab[(((size_t)(b * L + l)) << 9) + h * 64 + d] = vmb;
  __syncthreads();
  for (int i = tid; i < U * 64; i += 256) {
    int j = i >> 6, dd = i & 63;
    int row = mtop[bh * U + j];
    ab[(((size_t)(b * L + row)) << 9) + h * 64 + dd] = f2bf(updf[i] / den[j]);
  }
}

// ---------------- layernorm, 512 cols; bf16 in/resid; bf16/f32 out ---------
__global__ __launch_bounds__(256) void ln_kernel(const unsigned short* __restrict__ xinb,
    const unsigned short* __restrict__ residb, const float* __restrict__ g,
    const float* __restrict__ beta, unsigned short* __restrict__ xbout,
    float* __restrict__ xfout)
{
  size_t base = (size_t)blockIdx.x * 512; int tid = threadIdx.x;
  float v0 = 0.0f, v1 = 0.0f;
  if (xinb)   { v0 += bf2f(xinb[base + tid]); v1 += bf2f(xinb[base + 256 + tid]); }
  if (residb) { v0 += bf2f(residb[base + tid]); v1 += bf2f(residb[base + 256 + tid]); }
  __shared__ float red[256];
  __shared__ float smean, srstd;
  red[tid] = v0 + v1; __syncthreads();
  for (int s = 128; s > 0; s >>= 1) { if (tid < s) red[tid] += red[tid + s]; __syncthreads(); }
  if (tid == 0) smean = red[0] * (1.0f / 512.0f);
  __syncthreads();
  float m = smean;
  float d0 = v0 - m, d1 = v1 - m;
  red[tid] = d0 * d0 + d1 * d1; __syncthreads();
  for (int s = 128; s > 0; s >>= 1) { if (tid < s) red[tid] += red[tid + s]; __syncthreads(); }
  if (tid == 0) srstd = rsqrtf(red[0] * (1.0f / 512.0f) + 1e-5f);
  __syncthreads();
  float rs = srstd;
  float o0 = d0 * rs * g[tid] + beta[tid];
  float o1 = d1 * rs * g[tid + 256] + beta[tid + 256];
  if (xbout) { xbout[base + tid] = f2bf(o0); xbout[base + 256 + tid] = f2bf(o1); }
  if (xfout) { xfout[base + tid] = o0; xfout[base + 256 + tid] = o1; }
}

// ---------------- distil pool: bn-scale, elu, maxpool(3,2,pad1), bf16 in ---
__global__ void pool_kernel(const unsigned short* __restrict__ z, const float* __restrict__ g,
    const float* __restrict__ beta, unsigned short* __restrict__ xbout, int L, int count)
{
  int i = blockIdx.x * 256 + threadIdx.x;
  if (i >= count) return;
  int o = i & 511; int r1 = i >> 9;
  int Lh = L >> 1;
  int l2 = r1 % Lh; int b = r1 / Lh;
  const float invs = 0.99999500003749969f;
  float gg = g[o] * invs, bb = beta[o];
  float m = -3.0e38f;
#pragma unroll
  for (int w = -1; w <= 1; w++) {
    int l = 2 * l2 + w;
    if (l >= 0 && l < L) {
      float y = bf2f(z[(size_t)(b * L + l) * DM + o]) * gg + bb;
      y = (y > 0.0f) ? y : expm1f(y);
      m = fmaxf(m, y);
    }
  }
  xbout[(size_t)(b * Lh + l2) * DM + o] = f2bf(m);
}

// ---------------- misc ------------------------------------------------------
__global__ void cvt_kernel(const float* __restrict__ in, unsigned short* __restrict__ out, int n) {
  int i = blockIdx.x * 256 + threadIdx.x;
  if (i < n) out[i] = f2bf(in[i]);
}

__global__ void cvt_qkv(const float* __restrict__ src, unsigned short* __restrict__ dst, int matoff) {
  int i = blockIdx.x * 256 + threadIdx.x;
  if (i >= 786432) return;
  int layer = i >> 18; int rem = i & 262143;
  dst[(size_t)layer * 786432 + matoff + rem] = f2bf(src[i]);
}

__global__ void catbias(const float* __restrict__ bq, const float* __restrict__ bk,
                        const float* __restrict__ bv, float* __restrict__ dst) {
  int i = blockIdx.x * 256 + threadIdx.x;
  if (i >= 3 * 1536) return;
  int layer = i / 1536, c = i - layer * 1536;
  float v = (c < 512) ? bq[layer * 512 + c]
          : (c < 1024) ? bk[layer * 512 + c - 512]
          : bv[layer * 512 + c - 1024];
  dst[i] = v;
}

__global__ void repack_dcw(const float* __restrict__ dcw, unsigned short* __restrict__ wt, int n) {
  int i = blockIdx.x * 256 + threadIdx.x;
  if (i >= n) return;
  int t = i % 3; int rest = i / 3; int c = rest % 512; int lo = rest / 512;
  wt[(size_t)lo * 1536 + t * 512 + c] = f2bf(dcw[i]);
}

// ---- 2-stage deterministic mean over L=512 rows (f32 input) ----
__global__ void mean_part(const float* __restrict__ xin, float* __restrict__ part, int nblkPerB) {
  int blk = blockIdx.x;
  int b = blk / nblkPerB, pc = blk - b * nblkPerB;
  int tid = threadIdx.x;
  float s0 = 0.0f, s1 = 0.0f;
  int l0 = pc * 32;
  for (int r = 0; r < 32; r++) {
    size_t base = ((size_t)(b * 512 + l0 + r)) << 9;
    s0 += xin[base + tid];
    s1 += xin[base + 256 + tid];
  }
  part[((size_t)blk << 9) + tid] = s0;
  part[((size_t)blk << 9) + 256 + tid] = s1;
}
__global__ void mean_fin(const float* __restrict__ part, float* __restrict__ out,
                         int nblkPerB, int nb) {
  int i = blockIdx.x * 256 + threadIdx.x;
  if (i >= nb * 512) return;
  int b = i >> 9, d = i & 511;
  float s = 0.0f;
  for (int c = 0; c < nblkPerB; c++) s += part[((size_t)(b * nblkPerB + c) << 9) + d];
  out[i] = s * (1.0f / 512.0f);
}

// ---------------- host ------------------------------------------------------
extern "C" void kernel_launch(void* const* d_in, const int* in_sizes, int n_in,
                              void* d_out, int out_size, void* d_ws, size_t ws_size,
                              hipStream_t stream)
{
  (void)in_sizes; (void)n_in; (void)out_size;
  const float* x_enc = (const float*)d_in[0];
  const float* emb_w = (const float*)d_in[1];
  const float* wq   = (const float*)d_in[2];
  const float* bq   = (const float*)d_in[3];
  const float* wk   = (const float*)d_in[4];
  const float* bk   = (const float*)d_in[5];
  const float* wv   = (const float*)d_in[6];
  const float* bvv  = (const float*)d_in[7];
  const float* wo   = (const float*)d_in[8];
  const float* bo   = (const float*)d_in[9];
  const float* c1w  = (const float*)d_in[10];
  const float* c1b  = (const float*)d_in[11];
  const float* c2w  = (const float*)d_in[12];
  const float* c2b  = (const float*)d_in[13];
  const float* ln1g = (const float*)d_in[14];
  const float* ln1b = (const float*)d_in[15];
  const float* ln2g = (const float*)d_in[16];
  const float* ln2b = (const float*)d_in[17];
  const float* dcw  = (const float*)d_in[18];
  const float* dcb  = (const float*)d_in[19];
  const float* bng  = (const float*)d_in[20];
  const float* bnb  = (const float*)d_in[21];
  const float* lnfg = (const float*)d_in[22];
  const float* lnfb = (const float*)d_in[23];

  // ---- choose batch-chunk size: need = 16MB + nb*8.8MB ----
  int nb = 32;
  while (nb > 1 && (16777216ull + (size_t)nb * 8804352ull) > ws_size) nb >>= 1;

  // ---- fixed small region (first 16MB) ----
  char* ws = (char*)d_ws;
  size_t off = 0;
  unsigned short* WQKV = (unsigned short*)(ws + off); off += 4718592ull;
  unsigned short* WOB  = (unsigned short*)(ws + off); off += 1572864ull;
  unsigned short* C1WB = (unsigned short*)(ws + off); off += 1572864ull;
  unsigned short* C2WB = (unsigned short*)(ws + off); off += 1572864ull;
  unsigned short* WTB  = (unsigned short*)(ws + off); off += 3145728ull;
  float* BQKVB         = (float*)(ws + off);          off += 18432ull;
  float* MP            = (float*)(ws + off);          off += 2097152ull;
  int* IDXP            = (int*)(ws + off);            off += 589824ull;
  int* MTOPP           = (int*)(ws + off);            off += 24576ull;

  // ---- chunk region ----
  size_t cb = 16777216ull;
  unsigned short* Xbf  = (unsigned short*)(ws + cb);
  char* R              = ws + cb + (size_t)nb * 2097152ull;
  unsigned short* DQ   = (unsigned short*)R;
  unsigned short* DK   = (unsigned short*)(R + (size_t)nb * 2097152ull);
  unsigned short* DV   = (unsigned short*)(R + (size_t)nb * 4194304ull);
  unsigned short* TMPB = DQ;                             // bf16 GEMM out (Q dead)
  float* TMPF          = (float*)DK;                     // final-LN f32 (K dead)
  unsigned short* AB   = DV;                             // ctx/ffn-mid (V dead)
  float* PUPD          = (float*)(ws + cb + (size_t)nb * 8388608ull);
  float* PDEN          = (float*)((char*)PUPD + (size_t)nb * 393216ull);
  float* PVS           = (float*)((char*)PDEN + (size_t)nb * 6144ull);
  const size_t qkvs    = (size_t)nb * 1048576ull;

  // ---- weights to bf16 (once) ----
  {
    int nw = 3 * 512 * 512;
    int blocks = (nw + 255) / 256;
    cvt_qkv<<<blocks, 256, 0, stream>>>(wq, WQKV, 0);
    cvt_qkv<<<blocks, 256, 0, stream>>>(wk, WQKV, 262144);
    cvt_qkv<<<blocks, 256, 0, stream>>>(wv, WQKV, 524288);
    catbias<<<18, 256, 0, stream>>>(bq, bk, bvv, BQKVB);
    cvt_kernel<<<blocks, 256, 0, stream>>>(wo,  WOB,  nw);
    cvt_kernel<<<blocks, 256, 0, stream>>>(c1w, C1WB, nw);
    cvt_kernel<<<blocks, 256, 0, stream>>>(c2w, C2WB, nw);
    int nd = 2 * 512 * 512 * 3;
    repack_dcw<<<(nd + 255) / 256, 256, 0, stream>>>(dcw, WTB, nd);
  }

  // ---- sample indices per layer (once) ----
  for (int layer = 0; layer < 3; layer++) {
    int Ll = (layer == 0) ? 2048 : (layer == 1 ? 1024 : 512);
    int ul = (layer == 0) ? 24 : 21;
    uint32_t f0, f1, a0, b0k, a1, b1k;
    tf2x32(0u, 42u, 0u, (uint32_t)layer, &f0, &f1);
    tf2x32(f0, f1, 0u, 2u, &a0, &b0k);
    tf2x32(f0, f1, 1u, 3u, &a1, &b1k);
    (void)a0; (void)a1;
    int nhalf = Ll * ul / 2;
    idx_kernel<<<(nhalf + 255) / 256, 256, 0, stream>>>(IDXP + layer * 49152, nhalf, b0k, b1k, Ll - 1);
  }

  // ---- per-chunk full pipeline ----
  for (int b0 = 0; b0 < 32; b0 += nb) {
    embed_kernel<<<nb * 64, 256, 0, stream>>>(x_enc + (size_t)b0 * 2048 * 7, emb_w, Xbf);

    int L = 2048, Lsh = 11;
    for (int layer = 0; layer < 3; layer++) {
      const int M_ = nb * L;
      const int u = (layer == 0) ? 24 : 21;
      const int S = L >> 8;
      const int nbm = M_ / 128;
      const int ng  = 4 * nbm;
      const int ngq = 12 * nbm;
      const int xsg  = (ng  % 8 == 0) ? 1 : 0;
      const int xsgq = (ngq % 8 == 0) ? 1 : 0;
      const int xg = (nb % 8 == 0) ? 1 : 0;

      gemm_bt<3,0><<<ngq, 256, 0, stream>>>(Xbf, WQKV + (size_t)layer * 786432, BQKVB + layer * 1536, DQ, M_, 1536, 512, 0, 0, qkvs, 12, xsgq);

      if (u == 24) msamp_kernel<24><<<nb * (L / 16), 256, 0, stream>>>(DQ, DK, IDXP + layer * 49152, MP, L, L / 16, 1.0f / (float)L, xg);
      else         msamp_kernel<21><<<nb * (L / 16), 256, 0, stream>>>(DQ, DK, IDXP + layer * 49152, MP, L, L / 16, 1.0f / (float)L, xg);

      if (L == 2048)      topk_kernel<8><<<nb * 8, 256, 0, stream>>>(MP, MTOPP, L, u);
      else if (L == 1024) topk_kernel<4><<<nb * 8, 256, 0, stream>>>(MP, MTOPP, L, u);
      else                topk_kernel<2><<<nb * 8, 256, 0, stream>>>(MP, MTOPP, L, u);

      if (u == 24) {
        attn_part<24><<<nb * 8 * S, 256, 0, stream>>>(DQ, DK, DV, MTOPP, PUPD, PDEN, PVS, L, S);
        attn_comb<24><<<nb * 8, 256, 0, stream>>>(MTOPP, PUPD, PDEN, PVS, AB, L, S);
      } else {
        attn_part<21><<<nb * 8 * S, 256, 0, stream>>>(DQ, DK, DV, MTOPP, PUPD, PDEN, PVS, L, S);
        attn_comb<21><<<nb * 8, 256, 0, stream>>>(MTOPP, PUPD, PDEN, PVS, AB, L, S);
      }

      // Q/K/V dead; TMPB (=DQ) live from here.
      gemm_bt<1,0><<<ng, 256, 0, stream>>>(AB, WOB + (size_t)layer * 262144, bo + layer * 512, TMPB, M_, 512, 512, 0, 0, 0, 4, xsg);
      ln_kernel<<<M_, 256, 0, stream>>>(TMPB, Xbf, ln1g + layer * 512, ln1b + layer * 512, Xbf, nullptr);
      gemm_bt<2,0><<<ng, 256, 0, stream>>>(Xbf, C1WB + (size_t)layer * 262144, c1b + layer * 512, AB, M_, 512, 512, 0, 0, 0, 4, xsg);
      gemm_bt<1,0><<<ng, 256, 0, stream>>>(AB, C2WB + (size_t)layer * 262144, c2b + layer * 512, TMPB, M_, 512, 512, 0, 0, 0, 4, xsg);
      ln_kernel<<<M_, 256, 0, stream>>>(TMPB, Xbf, ln2g + layer * 512, ln2b + layer * 512, Xbf, nullptr);

      if (layer < 2) {
        gemm_bt<1,1><<<ng, 256, 0, stream>>>(Xbf, WTB + (size_t)layer * 786432, dcb + layer * 512, TMPB, M_, 512, 1536, L, Lsh, 0, 4, xsg);
        pool_kernel<<<nb * L, 256, 0, stream>>>(TMPB, bng + layer * 512, bnb + layer * 512, Xbf, L, nb * (L / 2) * 512);
        L >>= 1; Lsh -= 1;
      }
    }

    ln_kernel<<<nb * 512, 256, 0, stream>>>(nullptr, Xbf, lnfg, lnfb, nullptr, TMPF);
    mean_part<<<nb * 16, 256, 0, stream>>>(TMPF, MP, 16);
    mean_fin<<<(nb * 512 + 255) / 256, 256, 0, stream>>>(MP, (float*)d_out + (size_t)b0 * 512, 16, nb);
  }
}

// Round 15
// 2190.139 us; speedup vs baseline: 3.3194x; 3.3194x over previous
//
#include <hip/hip_runtime.h>
#include <stdint.h>

#define DM 512
#define DH 64

typedef __bf16 bf16x8 __attribute__((ext_vector_type(8)));
typedef float f32x4 __attribute__((ext_vector_type(4)));

__device__ __forceinline__ float bf2f(unsigned short h) {
  union { unsigned int u; float f; } c; c.u = ((unsigned int)h) << 16; return c.f;
}
__device__ __forceinline__ unsigned short f2bf(float f) {
  union { float f; unsigned int u; } c; c.f = f;
  unsigned int u = c.u;
  return (unsigned short)((u + 0x7FFFu + ((u >> 16) & 1u)) >> 16);
}
__device__ __forceinline__ void unpack8(uint4 v, float* f) {
  f[0] = bf2f((unsigned short)(v.x & 0xffff)); f[1] = bf2f((unsigned short)(v.x >> 16));
  f[2] = bf2f((unsigned short)(v.y & 0xffff)); f[3] = bf2f((unsigned short)(v.y >> 16));
  f[4] = bf2f((unsigned short)(v.z & 0xffff)); f[5] = bf2f((unsigned short)(v.z >> 16));
  f[6] = bf2f((unsigned short)(v.w & 0xffff)); f[7] = bf2f((unsigned short)(v.w >> 16));
}
__device__ __forceinline__ float dot8(uint4 kv, const float* qf) {
  float s;
  s  = bf2f((unsigned short)(kv.x & 0xffff)) * qf[0];
  s += bf2f((unsigned short)(kv.x >> 16))    * qf[1];
  s += bf2f((unsigned short)(kv.y & 0xffff)) * qf[2];
  s += bf2f((unsigned short)(kv.y >> 16))    * qf[3];
  s += bf2f((unsigned short)(kv.z & 0xffff)) * qf[4];
  s += bf2f((unsigned short)(kv.z >> 16))    * qf[5];
  s += bf2f((unsigned short)(kv.w & 0xffff)) * qf[6];
  s += bf2f((unsigned short)(kv.w >> 16))    * qf[7];
  return s;
}

// ---------------- Threefry-2x32 (20 rounds), JAX-compatible ----------------
__host__ __device__ inline void tf2x32(uint32_t k0, uint32_t k1, uint32_t x0, uint32_t x1,
                                       uint32_t* o0, uint32_t* o1) {
  uint32_t ks2 = k0 ^ k1 ^ 0x1BD11BDAu;
#define TFR(r) { x0 += x1; x1 = (x1 << r) | (x1 >> (32 - r)); x1 ^= x0; }
  x0 += k0; x1 += k1;
  TFR(13) TFR(15) TFR(26) TFR(6)
  x0 += k1; x1 += ks2 + 1u;
  TFR(17) TFR(29) TFR(16) TFR(24)
  x0 += ks2; x1 += k0 + 2u;
  TFR(13) TFR(15) TFR(26) TFR(6)
  x0 += k0; x1 += k1 + 3u;
  TFR(17) TFR(29) TFR(16) TFR(24)
  x0 += k1; x1 += ks2 + 4u;
  TFR(13) TFR(15) TFR(26) TFR(6)
  *o0 = x0 + ks2; *o1 = x1 + k0 + 5u;
#undef TFR
}

__global__ void idx_kernel(int* __restrict__ idx, int nhalf, unsigned int k0, unsigned int k1, int mask) {
  int m = blockIdx.x * 256 + threadIdx.x;
  if (m >= nhalf) return;
  uint32_t o0, o1;
  tf2x32(k0, k1, (uint32_t)m, (uint32_t)(m + nhalf), &o0, &o1);
  idx[m] = (int)(o0 & (uint32_t)mask);
  idx[m + nhalf] = (int)(o1 & (uint32_t)mask);
}

// ---------------- bf16 GEMM: C(M,N) = A(M,K) * B(N,K)^T + bias -------------
// 1D grid, XCD-bijective swizzle; bn = wgid % NBN (fast), bm = wgid / NBN.
// BK=64 (8 K-iters at K=512); XOR-swizzled LDS via pre-swizzled global src.
// Epilogue: fully unrolled (rule #20: runtime-indexed acc -> scratch!);
// C tile repacked through LDS -> coalesced 16B stores, 2 chunks/thread.
// EPI: 1 = bf16; 2 = gelu->bf16; 3 = bf16 QKV-split (col>>9 selects Q/K/V).
// CIRC: logical A row m, col k -> A[b*L + ((l-1+t) mod L)][k%512], t=k/512.
__device__ __forceinline__ void async_copy16(void* lds, const void* g) {
  __builtin_amdgcn_global_load_lds((const __attribute__((address_space(1))) unsigned int*)g,
                                   (__attribute__((address_space(3))) unsigned int*)lds,
                                   16, 0, 0);
}

template<int EPI, int CIRC>
__global__ __launch_bounds__(256) void gemm_bt(
    const unsigned short* __restrict__ A, const unsigned short* __restrict__ Bw,
    const float* __restrict__ bias, unsigned short* __restrict__ Cb,
    int M, int N, int K, int L, int Lsh, size_t qkvs, int NBN, int xswz)
{
  __shared__ unsigned short sA[128 * 64];
  __shared__ unsigned short sB[128 * 64];
  const int tid = threadIdx.x;
  const int wave = tid >> 6, lane = tid & 63;

  int blk = blockIdx.x;
  if (xswz) { int cpx = (int)gridDim.x >> 3; blk = (blk & 7) * cpx + (blk >> 3); }
  const int bn = blk % NBN, bm = blk / NBN;

  const int wm = (wave >> 1) << 6, wn = (wave & 1) << 6;

  const int srow = (wave << 5) + (lane >> 3);
  const int kb = (((lane & 7) ^ ((lane >> 3) & 7)) << 3);

  const unsigned short* gA = nullptr;
  int lI = 0;
  if constexpr (CIRC) {
    int r = bm * 128 + srow;
    lI = r & (L - 1);
  } else {
    gA = A + (size_t)(bm * 128 + srow) * K + kb;
  }
  const unsigned short* gB = Bw + (size_t)(bn * 128 + srow) * K + kb;

  f32x4 acc[4][4] = {};

  for (int k0 = 0; k0 < K; k0 += 64) {
#pragma unroll
    for (int q = 0; q < 4; q++) {
      unsigned short* ldsA = &sA[((wave << 5) + (q << 3)) << 6];
      unsigned short* ldsB = &sB[((wave << 5) + (q << 3)) << 6];
      if constexpr (CIRC) {
        int t = k0 >> 9;
        int kk = (k0 & 511) + kb;
        int sl = (lI + (q << 3) - 1 + t + L) & (L - 1);
        int bq = (bm * 128 + srow + (q << 3)) >> Lsh;
        async_copy16(ldsA, A + (((size_t)(bq * L + sl)) << 9) + kk);
      } else {
        async_copy16(ldsA, gA + (size_t)(q << 3) * K + k0);
      }
      async_copy16(ldsB, gB + (size_t)(q << 3) * K + k0);
    }
    __syncthreads();
#pragma unroll
    for (int kk = 0; kk < 2; kk++) {
      bf16x8 af[4], bfr[4];
#pragma unroll
      for (int i = 0; i < 4; i++) {
        int row = wm + (i << 4) + (lane & 15);
        int slot = ((kk << 2) + (lane >> 4)) ^ (lane & 7);
        af[i] = *(const bf16x8*)&sA[(row << 6) + (slot << 3)];
      }
#pragma unroll
      for (int j = 0; j < 4; j++) {
        int row = wn + (j << 4) + (lane & 15);
        int slot = ((kk << 2) + (lane >> 4)) ^ (lane & 7);
        bfr[j] = *(const bf16x8*)&sB[(row << 6) + (slot << 3)];
      }
#pragma unroll
      for (int i = 0; i < 4; i++)
#pragma unroll
        for (int j = 0; j < 4; j++)
          acc[i][j] = __builtin_amdgcn_mfma_f32_16x16x32_bf16(af[i], bfr[j], acc[i][j], 0, 0, 0);
    }
    __syncthreads();
  }

  // ---- epilogue: LDS repack, coalesced stores (FULLY UNROLLED, acc static) ----
  unsigned short* sOut = sA;                 // 32 rows x stride 136
  const int cr = (lane >> 4) << 2;
  const int cc = lane & 15;
  const int lrb = ((wave >> 1) << 4) + cr;
  const int lr = tid >> 3, ch0 = tid & 7;
#pragma unroll
  for (int i = 0; i < 4; i++) {
    if (i) __syncthreads();
#pragma unroll
    for (int j = 0; j < 4; j++) {
      const int col = wn + (j << 4) + cc;
      const float bvv = bias[(bn << 7) + col];
#pragma unroll
      for (int r = 0; r < 4; r++) {
        float v = acc[i][j][r] + bvv;
        if constexpr (EPI == 2) {
          v = 0.5f * v * (1.0f + erff(v * 0.70710678118654752f));
        }
        sOut[(lrb + r) * 136 + col] = f2bf(v);
      }
    }
    __syncthreads();
    int grow = (bm << 7) + ((lr >> 4) << 6) + (i << 4) + (lr & 15);
#pragma unroll
    for (int cpart = 0; cpart < 2; cpart++) {
      int ch = ch0 + (cpart << 3);
      uint4 val = *(const uint4*)&sOut[lr * 136 + (ch << 3)];
      if constexpr (EPI == 3) {
        int gcol = (bn << 7) + (ch << 3);
        *(uint4*)&Cb[(size_t)(gcol >> 9) * qkvs + ((size_t)grow << 9) + (gcol & 511)] = val;
      } else {
        *(uint4*)&Cb[(size_t)grow * N + (bn << 7) + (ch << 3)] = val;
      }
    }
  }
}

// ---------------- embedding circular conv (C=7, W=3) -> bf16 ---------------
__global__ __launch_bounds__(256) void embed_kernel(const float* __restrict__ xe,
    const float* __restrict__ w, unsigned short* __restrict__ xb)
{
  int blk = blockIdx.x;             // nb * 64
  int b = blk >> 6, lg = blk & 63;
  int l0 = lg << 5;
  int tid = threadIdx.x;
  __shared__ float xwin[34 * 7];
  for (int i = tid; i < 34 * 7; i += 256) {
    int r = i / 7, c = i - r * 7;
    int sl = (l0 - 1 + r) & 2047;
    xwin[i] = xe[((size_t)(b * 2048 + sl)) * 7 + c];
  }
  __syncthreads();
  float wr0[21], wr1[21];
  const float* w0 = w + tid * 21;
  const float* w1 = w + (tid + 256) * 21;
#pragma unroll
  for (int k = 0; k < 21; k++) { wr0[k] = w0[k]; wr1[k] = w1[k]; }
#pragma unroll 1
  for (int ll = 0; ll < 32; ll++) {
    float a0 = 0.0f, a1 = 0.0f;
#pragma unroll
    for (int c = 0; c < 7; c++)
#pragma unroll
      for (int t = 0; t < 3; t++) {
        float xv = xwin[(ll + t) * 7 + c];
        a0 += xv * wr0[c * 3 + t];
        a1 += xv * wr1[c * 3 + t];
      }
    size_t o = ((size_t)(b * 2048 + l0 + ll)) << 9;
    xb[o + tid] = f2bf(a0);
    xb[o + 256 + tid] = f2bf(a1);
  }
}

// ---------------- M = max_j(qk_samp) - sum_j(qk_samp)/L --------------------
template<int U>
__global__ __launch_bounds__(256) void msamp_kernel(
    const unsigned short* __restrict__ qb, const unsigned short* __restrict__ kbuf,
    const int* __restrict__ idx, float* __restrict__ Mv, int L, int nlc, float invL,
    int xcdgrp)
{
  const int RB = 16;
  int blk = blockIdx.x;
  int b, lc;
  if (xcdgrp) {
    int xcd = blk & 7, slot = blk >> 3;
    int g = slot / nlc; lc = slot - g * nlc;
    b = g * 8 + xcd;
  } else {
    b = blk / nlc; lc = blk - b * nlc;
  }
  int l0 = lc * RB;
  int tid = threadIdx.x;
  int wave = tid >> 6, lane = tid & 63;
  int p = lane & 7, h = lane >> 3;
  __shared__ int iidx[RB * U];
  __shared__ float pM[RB * 8 * 25];

  for (int i = tid; i < RB * U; i += 256) iidx[i] = idx[l0 * U + i];
  __syncthreads();

  const size_t rowbase = ((size_t)(b * L)) << 9;
#pragma unroll
  for (int r = 0; r < RB / 4; r++) {
    int l = wave * (RB / 4) + r;
    uint4 qv = *(const uint4*)(qb + rowbase + (((size_t)(l0 + l)) << 9) + (lane << 3));
    float qf[8]; unpack8(qv, qf);
    int kr[U];
#pragma unroll
    for (int j = 0; j < U; j++) kr[j] = iidx[l * U + j];
#pragma unroll
    for (int j = 0; j < U; j++) {
      uint4 kv = *(const uint4*)(kbuf + rowbase + (((size_t)kr[j]) << 9) + (lane << 3));
      float s = dot8(kv, qf);
      s += __shfl_xor(s, 1);
      s += __shfl_xor(s, 2);
      s += __shfl_xor(s, 4);
      if (p == 0) pM[(l * 8 + h) * 25 + j] = s;
    }
  }
  __syncthreads();

  if (tid < RB * 8) {
    int l = tid >> 3, hh = tid & 7;
    float mx = -3.0e38f, sm = 0.0f;
    const float* pr = &pM[tid * 25];
    for (int j = 0; j < U; j++) { float v = pr[j]; mx = fmaxf(mx, v); sm += v; }
    Mv[((size_t)((b << 3) + hh)) * L + l0 + l] = mx - sm * invL;
  }
}

// ---------------- top-u: register-resident, shuffle-reduce -----------------
template<int S>
__global__ __launch_bounds__(256) void topk_kernel(const float* __restrict__ Mv,
    int* __restrict__ mtop, int L, int u)
{
  int bh = blockIdx.x; int tid = threadIdx.x;
  int wave = tid >> 6, lane = tid & 63;
  float lv[S];
#pragma unroll
  for (int s = 0; s < S; s++) lv[s] = Mv[(size_t)bh * L + s * 256 + tid];
  __shared__ float sv[4];
  __shared__ int si[4];
  for (int t = 0; t < u; t++) {
    float bv = lv[0]; int bs = 0;
#pragma unroll
    for (int s = 1; s < S; s++) if (lv[s] > bv) { bv = lv[s]; bs = s; }
    int bi = bs * 256 + tid;
#pragma unroll
    for (int o = 1; o < 64; o <<= 1) {
      float ov = __shfl_xor(bv, o); int oi = __shfl_xor(bi, o);
      if (ov > bv || (ov == bv && oi < bi)) { bv = ov; bi = oi; }
    }
    if (lane == 0) { sv[wave] = bv; si[wave] = bi; }
    __syncthreads();
    float wv = sv[0]; int wi = si[0];
#pragma unroll
    for (int w = 1; w < 4; w++) {
      float ov = sv[w]; int oi = si[w];
      if (ov > wv || (ov == wv && oi < wi)) { wv = ov; wi = oi; }
    }
    if (tid == 0) mtop[bh * u + t] = wi;
#pragma unroll
    for (int s = 0; s < S; s++)
      if (s == (wi >> 8) && (wi & 255) == tid) lv[s] = -3.0e38f;
    __syncthreads();
  }
}

// ---------------- attention part: one 256-row K/V chunk per block ----------
template<int U>
__device__ __forceinline__ void dot_rows(const unsigned short* __restrict__ krow,
                                         const float* __restrict__ qred, float* s)
{
#pragma unroll
  for (int j = 0; j < U; j++) s[j] = 0.0f;
  const uint4* kv4 = (const uint4*)krow;
#pragma unroll
  for (int d8 = 0; d8 < 8; d8++) {
    uint4 kv = kv4[d8];
    float kf[8];
    kf[0] = bf2f((unsigned short)(kv.x & 0xffff)); kf[1] = bf2f((unsigned short)(kv.x >> 16));
    kf[2] = bf2f((unsigned short)(kv.y & 0xffff)); kf[3] = bf2f((unsigned short)(kv.y >> 16));
    kf[4] = bf2f((unsigned short)(kv.z & 0xffff)); kf[5] = bf2f((unsigned short)(kv.z >> 16));
    kf[6] = bf2f((unsigned short)(kv.w & 0xffff)); kf[7] = bf2f((unsigned short)(kv.w >> 16));
#pragma unroll
    for (int j = 0; j < U; j++) {
      const float4 q0 = *(const float4*)&qred[j * 64 + d8 * 8];
      const float4 q1 = *(const float4*)&qred[j * 64 + d8 * 8 + 4];
      s[j] += kf[0] * q0.x + kf[1] * q0.y + kf[2] * q0.z + kf[3] * q0.w
            + kf[4] * q1.x + kf[5] * q1.y + kf[6] * q1.z + kf[7] * q1.w;
    }
  }
}

template<int U>
__global__ __launch_bounds__(256) void attn_part(
    const unsigned short* __restrict__ qb, const unsigned short* __restrict__ kbuf,
    const unsigned short* __restrict__ vbuf, const int* __restrict__ mtop,
    float* __restrict__ pupd, float* __restrict__ pden, float* __restrict__ pvs,
    int L, int S)
{
  int blk = blockIdx.x;
  int bh = blk / S, split = blk - bh * S;
  int b = bh >> 3, h = bh & 7;
  int tid = threadIdx.x;
  __shared__ float qred[U * 64];
  __shared__ float pA[U * 4 * 66];
  __shared__ float pB[U * 256];
  __shared__ float pC[256];
  __shared__ float dnred[4 * U];

  for (int i = tid; i < U * 64; i += 256) {
    int j = i >> 6, d = i & 63;
    int row = mtop[bh * U + j];
    qred[i] = bf2f(qb[(((size_t)(b * L + row)) << 9) + h * 64 + d]) * 0.125f;
  }
  __syncthreads();

  int l = (split << 8) + tid;
  {
    float s[U];
    dot_rows<U>(kbuf + (((size_t)(b * L + l)) << 9) + h * 64, qred, s);
    int g0 = tid >> 6, d0 = tid & 63;
#pragma unroll
    for (int j = 0; j < U; j++) pA[(j * 4 + g0) * 66 + d0] = expf(s[j]);
  }
  __syncthreads();

  int g = tid >> 6, d = tid & 63;
  const unsigned short* vcol = vbuf + (((size_t)(b * L)) << 9) + h * 64 + d;
  float lupd[U], ldn[U]; float lvs = 0.0f;
#pragma unroll
  for (int j = 0; j < U; j++) { lupd[j] = 0.0f; ldn[j] = 0.0f; }
#pragma unroll 1
  for (int li = 0; li < 64; li++) {
    int ll = (split << 8) + (g << 6) + li;
    float vd = bf2f(vcol[(size_t)ll << 9]);
    lvs += vd;
#pragma unroll
    for (int j = 0; j < U; j++) {
      float pv = pA[(j * 4 + g) * 66 + li];
      ldn[j] += pv; lupd[j] += pv * vd;
    }
  }
  if (d == 0) {
#pragma unroll
    for (int j = 0; j < U; j++) dnred[g * U + j] = ldn[j];
  }
#pragma unroll
  for (int j = 0; j < U; j++) pB[(g * U + j) * 64 + d] = lupd[j];
  pC[tid] = lvs;
  __syncthreads();

  size_t base = (size_t)bh * S + split;
  for (int i = tid; i < U * 64; i += 256) {
    int j = i >> 6, dd = i & 63;
    pupd[base * (U * 64) + i] = pB[j * 64 + dd] + pB[(U + j) * 64 + dd]
                              + pB[(2 * U + j) * 64 + dd] + pB[(3 * U + j) * 64 + dd];
  }
  if (tid < U)
    pden[base * U + tid] = dnred[tid] + dnred[U + tid] + dnred[2 * U + tid] + dnred[3 * U + tid];
  if (tid < 64)
    pvs[base * 64 + tid] = pC[tid] + pC[64 + tid] + pC[128 + tid] + pC[192 + tid];
}

// ---------------- attention combine: vmean bcast + top-row scatter ---------
template<int U>
__global__ __launch_bounds__(256) void attn_comb(
    const int* __restrict__ mtop, const float* __restrict__ pupd,
    const float* __restrict__ pden, const float* __restrict__ pvs,
    unsigned short* __restrict__ ab, int L, int S)
{
  int bh = blockIdx.x; int b = bh >> 3, h = bh & 7;
  int tid = threadIdx.x;
  __shared__ float updf[U * 64];
  __shared__ float den[U];
  __shared__ float vm[64];
  for (int i = tid; i < U * 64; i += 256) {
    float s = 0.0f;
    for (int sp = 0; sp < S; sp++) s += pupd[((size_t)bh * S + sp) * (U * 64) + i];
    updf[i] = s;
  }
  if (tid < U) {
    float s = 0.0f;
    for (int sp = 0; sp < S; sp++) s += pden[((size_t)bh * S + sp) * U + tid];
    den[tid] = s;
  }
  if (tid < 64) {
    float s = 0.0f;
    for (int sp = 0; sp < S; sp++) s += pvs[((size_t)bh * S + sp) * 64 + tid];
    vm[tid] = s / (float)L;
  }
  __syncthreads();
  int g = tid >> 6, d = tid & 63;
  unsigned short vmb = f2bf(vm[d]);
  for (int l = g; l < L; l += 4)
    ab[(((size_t)(b * L + l)) << 9) + h * 64 + d] = vmb;
  __syncthreads();
  for (int i = tid; i < U * 64; i += 256) {
    int j = i >> 6, dd = i & 63;
    int row = mtop[bh * U + j];
    ab[(((size_t)(b * L + row)) << 9) + h * 64 + dd] = f2bf(updf[i] / den[j]);
  }
}

// ---------------- layernorm, 512 cols; bf16 in/resid; bf16/f32 out ---------
__global__ __launch_bounds__(256) void ln_kernel(const unsigned short* __restrict__ xinb,
    const unsigned short* __restrict__ residb, const float* __restrict__ g,
    const float* __restrict__ beta, unsigned short* __restrict__ xbout,
    float* __restrict__ xfout)
{
  size_t base = (size_t)blockIdx.x * 512; int tid = threadIdx.x;
  float v0 = 0.0f, v1 = 0.0f;
  if (xinb)   { v0 += bf2f(xinb[base + tid]); v1 += bf2f(xinb[base + 256 + tid]); }
  if (residb) { v0 += bf2f(residb[base + tid]); v1 += bf2f(residb[base + 256 + tid]); }
  __shared__ float red[256];
  __shared__ float smean, srstd;
  red[tid] = v0 + v1; __syncthreads();
  for (int s = 128; s > 0; s >>= 1) { if (tid < s) red[tid] += red[tid + s]; __syncthreads(); }
  if (tid == 0) smean = red[0] * (1.0f / 512.0f);
  __syncthreads();
  float m = smean;
  float d0 = v0 - m, d1 = v1 - m;
  red[tid] = d0 * d0 + d1 * d1; __syncthreads();
  for (int s = 128; s > 0; s >>= 1) { if (tid < s) red[tid] += red[tid + s]; __syncthreads(); }
  if (tid == 0) srstd = rsqrtf(red[0] * (1.0f / 512.0f) + 1e-5f);
  __syncthreads();
  float rs = srstd;
  float o0 = d0 * rs * g[tid] + beta[tid];
  float o1 = d1 * rs * g[tid + 256] + beta[tid + 256];
  if (xbout) { xbout[base + tid] = f2bf(o0); xbout[base + 256 + tid] = f2bf(o1); }
  if (xfout) { xfout[base + tid] = o0; xfout[base + 256 + tid] = o1; }
}

// ---------------- distil pool: bn-scale, elu, maxpool(3,2,pad1), bf16 in ---
__global__ void pool_kernel(const unsigned short* __restrict__ z, const float* __restrict__ g,
    const float* __restrict__ beta, unsigned short* __restrict__ xbout, int L, int count)
{
  int i = blockIdx.x * 256 + threadIdx.x;
  if (i >= count) return;
  int o = i & 511; int r1 = i >> 9;
  int Lh = L >> 1;
  int l2 = r1 % Lh; int b = r1 / Lh;
  const float invs = 0.99999500003749969f;
  float gg = g[o] * invs, bb = beta[o];
  float m = -3.0e38f;
#pragma unroll
  for (int w = -1; w <= 1; w++) {
    int l = 2 * l2 + w;
    if (l >= 0 && l < L) {
      float y = bf2f(z[(size_t)(b * L + l) * DM + o]) * gg + bb;
      y = (y > 0.0f) ? y : expm1f(y);
      m = fmaxf(m, y);
    }
  }
  xbout[(size_t)(b * Lh + l2) * DM + o] = f2bf(m);
}

// ---------------- misc ------------------------------------------------------
__global__ void cvt_kernel(const float* __restrict__ in, unsigned short* __restrict__ out, int n) {
  int i = blockIdx.x * 256 + threadIdx.x;
  if (i < n) out[i] = f2bf(in[i]);
}

__global__ void cvt_qkv(const float* __restrict__ src, unsigned short* __restrict__ dst, int matoff) {
  int i = blockIdx.x * 256 + threadIdx.x;
  if (i >= 786432) return;
  int layer = i >> 18; int rem = i & 262143;
  dst[(size_t)layer * 786432 + matoff + rem] = f2bf(src[i]);
}

__global__ void catbias(const float* __restrict__ bq, const float* __restrict__ bk,
                        const float* __restrict__ bv, float* __restrict__ dst) {
  int i = blockIdx.x * 256 + threadIdx.x;
  if (i >= 3 * 1536) return;
  int layer = i / 1536, c = i - layer * 1536;
  float v = (c < 512) ? bq[layer * 512 + c]
          : (c < 1024) ? bk[layer * 512 + c - 512]
          : bv[layer * 512 + c - 1024];
  dst[i] = v;
}

__global__ void repack_dcw(const float* __restrict__ dcw, unsigned short* __restrict__ wt, int n) {
  int i = blockIdx.x * 256 + threadIdx.x;
  if (i >= n) return;
  int t = i % 3; int rest = i / 3; int c = rest % 512; int lo = rest / 512;
  wt[(size_t)lo * 1536 + t * 512 + c] = f2bf(dcw[i]);
}

// ---- 2-stage deterministic mean over L=512 rows (f32 input) ----
__global__ void mean_part(const float* __restrict__ xin, float* __restrict__ part, int nblkPerB) {
  int blk = blockIdx.x;
  int b = blk / nblkPerB, pc = blk - b * nblkPerB;
  int tid = threadIdx.x;
  float s0 = 0.0f, s1 = 0.0f;
  int l0 = pc * 32;
  for (int r = 0; r < 32; r++) {
    size_t base = ((size_t)(b * 512 + l0 + r)) << 9;
    s0 += xin[base + tid];
    s1 += xin[base + 256 + tid];
  }
  part[((size_t)blk << 9) + tid] = s0;
  part[((size_t)blk << 9) + 256 + tid] = s1;
}
__global__ void mean_fin(const float* __restrict__ part, float* __restrict__ out,
                         int nblkPerB, int nb) {
  int i = blockIdx.x * 256 + threadIdx.x;
  if (i >= nb * 512) return;
  int b = i >> 9, d = i & 511;
  float s = 0.0f;
  for (int c = 0; c < nblkPerB; c++) s += part[((size_t)(b * nblkPerB + c) << 9) + d];
  out[i] = s * (1.0f / 512.0f);
}

// ---------------- host ------------------------------------------------------
extern "C" void kernel_launch(void* const* d_in, const int* in_sizes, int n_in,
                              void* d_out, int out_size, void* d_ws, size_t ws_size,
                              hipStream_t stream)
{
  (void)in_sizes; (void)n_in; (void)out_size;
  const float* x_enc = (const float*)d_in[0];
  const float* emb_w = (const float*)d_in[1];
  const float* wq   = (const float*)d_in[2];
  const float* bq   = (const float*)d_in[3];
  const float* wk   = (const float*)d_in[4];
  const float* bk   = (const float*)d_in[5];
  const float* wv   = (const float*)d_in[6];
  const float* bvv  = (const float*)d_in[7];
  const float* wo   = (const float*)d_in[8];
  const float* bo   = (const float*)d_in[9];
  const float* c1w  = (const float*)d_in[10];
  const float* c1b  = (const float*)d_in[11];
  const float* c2w  = (const float*)d_in[12];
  const float* c2b  = (const float*)d_in[13];
  const float* ln1g = (const float*)d_in[14];
  const float* ln1b = (const float*)d_in[15];
  const float* ln2g = (const float*)d_in[16];
  const float* ln2b = (const float*)d_in[17];
  const float* dcw  = (const float*)d_in[18];
  const float* dcb  = (const float*)d_in[19];
  const float* bng  = (const float*)d_in[20];
  const float* bnb  = (const float*)d_in[21];
  const float* lnfg = (const float*)d_in[22];
  const float* lnfb = (const float*)d_in[23];

  // ---- choose batch-chunk size: need = 16MB + nb*8.8MB ----
  int nb = 32;
  while (nb > 1 && (16777216ull + (size_t)nb * 8804352ull) > ws_size) nb >>= 1;

  // ---- fixed small region (first 16MB) ----
  char* ws = (char*)d_ws;
  size_t off = 0;
  unsigned short* WQKV = (unsigned short*)(ws + off); off += 4718592ull;
  unsigned short* WOB  = (unsigned short*)(ws + off); off += 1572864ull;
  unsigned short* C1WB = (unsigned short*)(ws + off); off += 1572864ull;
  unsigned short* C2WB = (unsigned short*)(ws + off); off += 1572864ull;
  unsigned short* WTB  = (unsigned short*)(ws + off); off += 3145728ull;
  float* BQKVB         = (float*)(ws + off);          off += 18432ull;
  float* MP            = (float*)(ws + off);          off += 2097152ull;
  int* IDXP            = (int*)(ws + off);            off += 589824ull;
  int* MTOPP           = (int*)(ws + off);            off += 24576ull;

  // ---- chunk region ----
  size_t cb = 16777216ull;
  unsigned short* Xbf  = (unsigned short*)(ws + cb);
  char* R              = ws + cb + (size_t)nb * 2097152ull;
  unsigned short* DQ   = (unsigned short*)R;
  unsigned short* DK   = (unsigned short*)(R + (size_t)nb * 2097152ull);
  unsigned short* DV   = (unsigned short*)(R + (size_t)nb * 4194304ull);
  unsigned short* TMPB = DQ;                             // bf16 GEMM out (Q dead)
  float* TMPF          = (float*)DK;                     // final-LN f32 (K dead)
  unsigned short* AB   = DV;                             // ctx/ffn-mid (V dead)
  float* PUPD          = (float*)(ws + cb + (size_t)nb * 8388608ull);
  float* PDEN          = (float*)((char*)PUPD + (size_t)nb * 393216ull);
  float* PVS           = (float*)((char*)PDEN + (size_t)nb * 6144ull);
  const size_t qkvs    = (size_t)nb * 1048576ull;

  // ---- weights to bf16 (once) ----
  {
    int nw = 3 * 512 * 512;
    int blocks = (nw + 255) / 256;
    cvt_qkv<<<blocks, 256, 0, stream>>>(wq, WQKV, 0);
    cvt_qkv<<<blocks, 256, 0, stream>>>(wk, WQKV, 262144);
    cvt_qkv<<<blocks, 256, 0, stream>>>(wv, WQKV, 524288);
    catbias<<<18, 256, 0, stream>>>(bq, bk, bvv, BQKVB);
    cvt_kernel<<<blocks, 256, 0, stream>>>(wo,  WOB,  nw);
    cvt_kernel<<<blocks, 256, 0, stream>>>(c1w, C1WB, nw);
    cvt_kernel<<<blocks, 256, 0, stream>>>(c2w, C2WB, nw);
    int nd = 2 * 512 * 512 * 3;
    repack_dcw<<<(nd + 255) / 256, 256, 0, stream>>>(dcw, WTB, nd);
  }

  // ---- sample indices per layer (once) ----
  for (int layer = 0; layer < 3; layer++) {
    int Ll = (layer == 0) ? 2048 : (layer == 1 ? 1024 : 512);
    int ul = (layer == 0) ? 24 : 21;
    uint32_t f0, f1, a0, b0k, a1, b1k;
    tf2x32(0u, 42u, 0u, (uint32_t)layer, &f0, &f1);
    tf2x32(f0, f1, 0u, 2u, &a0, &b0k);
    tf2x32(f0, f1, 1u, 3u, &a1, &b1k);
    (void)a0; (void)a1;
    int nhalf = Ll * ul / 2;
    idx_kernel<<<(nhalf + 255) / 256, 256, 0, stream>>>(IDXP + layer * 49152, nhalf, b0k, b1k, Ll - 1);
  }

  // ---- per-chunk full pipeline ----
  for (int b0 = 0; b0 < 32; b0 += nb) {
    embed_kernel<<<nb * 64, 256, 0, stream>>>(x_enc + (size_t)b0 * 2048 * 7, emb_w, Xbf);

    int L = 2048, Lsh = 11;
    for (int layer = 0; layer < 3; layer++) {
      const int M_ = nb * L;
      const int u = (layer == 0) ? 24 : 21;
      const int S = L >> 8;
      const int nbm = M_ / 128;
      const int ng  = 4 * nbm;
      const int ngq = 12 * nbm;
      const int xsg  = (ng  % 8 == 0) ? 1 : 0;
      const int xsgq = (ngq % 8 == 0) ? 1 : 0;
      const int xg = (nb % 8 == 0) ? 1 : 0;

      gemm_bt<3,0><<<ngq, 256, 0, stream>>>(Xbf, WQKV + (size_t)layer * 786432, BQKVB + layer * 1536, DQ, M_, 1536, 512, 0, 0, qkvs, 12, xsgq);

      if (u == 24) msamp_kernel<24><<<nb * (L / 16), 256, 0, stream>>>(DQ, DK, IDXP + layer * 49152, MP, L, L / 16, 1.0f / (float)L, xg);
      else         msamp_kernel<21><<<nb * (L / 16), 256, 0, stream>>>(DQ, DK, IDXP + layer * 49152, MP, L, L / 16, 1.0f / (float)L, xg);

      if (L == 2048)      topk_kernel<8><<<nb * 8, 256, 0, stream>>>(MP, MTOPP, L, u);
      else if (L == 1024) topk_kernel<4><<<nb * 8, 256, 0, stream>>>(MP, MTOPP, L, u);
      else                topk_kernel<2><<<nb * 8, 256, 0, stream>>>(MP, MTOPP, L, u);

      if (u == 24) {
        attn_part<24><<<nb * 8 * S, 256, 0, stream>>>(DQ, DK, DV, MTOPP, PUPD, PDEN, PVS, L, S);
        attn_comb<24><<<nb * 8, 256, 0, stream>>>(MTOPP, PUPD, PDEN, PVS, AB, L, S);
      } else {
        attn_part<21><<<nb * 8 * S, 256, 0, stream>>>(DQ, DK, DV, MTOPP, PUPD, PDEN, PVS, L, S);
        attn_comb<21><<<nb * 8, 256, 0, stream>>>(MTOPP, PUPD, PDEN, PVS, AB, L, S);
      }

      // Q/K/V dead; TMPB (=DQ) live from here.
      gemm_bt<1,0><<<ng, 256, 0, stream>>>(AB, WOB + (size_t)layer * 262144, bo + layer * 512, TMPB, M_, 512, 512, 0, 0, 0, 4, xsg);
      ln_kernel<<<M_, 256, 0, stream>>>(TMPB, Xbf, ln1g + layer * 512, ln1b + layer * 512, Xbf, nullptr);
      gemm_bt<2,0><<<ng, 256, 0, stream>>>(Xbf, C1WB + (size_t)layer * 262144, c1b + layer * 512, AB, M_, 512, 512, 0, 0, 0, 4, xsg);
      gemm_bt<1,0><<<ng, 256, 0, stream>>>(AB, C2WB + (size_t)layer * 262144, c2b + layer * 512, TMPB, M_, 512, 512, 0, 0, 0, 4, xsg);
      ln_kernel<<<M_, 256, 0, stream>>>(TMPB, Xbf, ln2g + layer * 512, ln2b + layer * 512, Xbf, nullptr);

      if (layer < 2) {
        gemm_bt<1,1><<<ng, 256, 0, stream>>>(Xbf, WTB + (size_t)layer * 786432, dcb + layer * 512, TMPB, M_, 512, 1536, L, Lsh, 0, 4, xsg);
        pool_kernel<<<nb * L, 256, 0, stream>>>(TMPB, bng + layer * 512, bnb + layer * 512, Xbf, L, nb * (L / 2) * 512);
        L >>= 1; Lsh -= 1;
      }
    }

    ln_kernel<<<nb * 512, 256, 0, stream>>>(nullptr, Xbf, lnfg, lnfb, nullptr, TMPF);
    mean_part<<<nb * 16, 256, 0, stream>>>(TMPF, MP, 16);
    mean_fin<<<(nb * 512 + 255) / 256, 256, 0, stream>>>(MP, (float*)d_out + (size_t)b0 * 512, 16, nb);
  }
}

// Round 16
// 2171.440 us; speedup vs baseline: 3.3480x; 1.0086x over previous
//
#include <hip/hip_runtime.h>
#include <stdint.h>

#define DM 512
#define DH 64

typedef __bf16 bf16x8 __attribute__((ext_vector_type(8)));
typedef float f32x4 __attribute__((ext_vector_type(4)));

__device__ __forceinline__ float bf2f(unsigned short h) {
  union { unsigned int u; float f; } c; c.u = ((unsigned int)h) << 16; return c.f;
}
__device__ __forceinline__ unsigned short f2bf(float f) {
  union { float f; unsigned int u; } c; c.f = f;
  unsigned int u = c.u;
  return (unsigned short)((u + 0x7FFFu + ((u >> 16) & 1u)) >> 16);
}
__device__ __forceinline__ void unpack8(uint4 v, float* f) {
  f[0] = bf2f((unsigned short)(v.x & 0xffff)); f[1] = bf2f((unsigned short)(v.x >> 16));
  f[2] = bf2f((unsigned short)(v.y & 0xffff)); f[3] = bf2f((unsigned short)(v.y >> 16));
  f[4] = bf2f((unsigned short)(v.z & 0xffff)); f[5] = bf2f((unsigned short)(v.z >> 16));
  f[6] = bf2f((unsigned short)(v.w & 0xffff)); f[7] = bf2f((unsigned short)(v.w >> 16));
}
__device__ __forceinline__ float dot8(uint4 kv, const float* qf) {
  float s;
  s  = bf2f((unsigned short)(kv.x & 0xffff)) * qf[0];
  s += bf2f((unsigned short)(kv.x >> 16))    * qf[1];
  s += bf2f((unsigned short)(kv.y & 0xffff)) * qf[2];
  s += bf2f((unsigned short)(kv.y >> 16))    * qf[3];
  s += bf2f((unsigned short)(kv.z & 0xffff)) * qf[4];
  s += bf2f((unsigned short)(kv.z >> 16))    * qf[5];
  s += bf2f((unsigned short)(kv.w & 0xffff)) * qf[6];
  s += bf2f((unsigned short)(kv.w >> 16))    * qf[7];
  return s;
}

// ---------------- Threefry-2x32 (20 rounds), JAX-compatible ----------------
__host__ __device__ inline void tf2x32(uint32_t k0, uint32_t k1, uint32_t x0, uint32_t x1,
                                       uint32_t* o0, uint32_t* o1) {
  uint32_t ks2 = k0 ^ k1 ^ 0x1BD11BDAu;
#define TFR(r) { x0 += x1; x1 = (x1 << r) | (x1 >> (32 - r)); x1 ^= x0; }
  x0 += k0; x1 += k1;
  TFR(13) TFR(15) TFR(26) TFR(6)
  x0 += k1; x1 += ks2 + 1u;
  TFR(17) TFR(29) TFR(16) TFR(24)
  x0 += ks2; x1 += k0 + 2u;
  TFR(13) TFR(15) TFR(26) TFR(6)
  x0 += k0; x1 += k1 + 3u;
  TFR(17) TFR(29) TFR(16) TFR(24)
  x0 += k1; x1 += ks2 + 4u;
  TFR(13) TFR(15) TFR(26) TFR(6)
  *o0 = x0 + ks2; *o1 = x1 + k0 + 5u;
#undef TFR
}

__global__ void idx_kernel(int* __restrict__ idx, int nhalf, unsigned int k0, unsigned int k1, int mask) {
  int m = blockIdx.x * 256 + threadIdx.x;
  if (m >= nhalf) return;
  uint32_t o0, o1;
  tf2x32(k0, k1, (uint32_t)m, (uint32_t)(m + nhalf), &o0, &o1);
  idx[m] = (int)(o0 & (uint32_t)mask);
  idx[m + nhalf] = (int)(o1 & (uint32_t)mask);
}

// ---------------- bf16 GEMM: C(M,N) = A(M,K) * B(N,K)^T + bias -------------
// 1D grid, XCD-bijective swizzle; bn = wgid % NBN (fast), bm = wgid / NBN.
// BK=64 (8 K-iters at K=512); XOR-swizzled LDS via pre-swizzled global src.
// Epilogue: fully unrolled (rule #20); LDS-repacked coalesced 16B stores.
// EPI: 1 = bf16; 2 = gelu->bf16; 3 = bf16 QKV-split (col>>9 selects Q/K/V).
// CIRC: logical A row m, col k -> A[b*L + ((l-1+t) mod L)][k%512], t=k/512.
__device__ __forceinline__ void async_copy16(void* lds, const void* g) {
  __builtin_amdgcn_global_load_lds((const __attribute__((address_space(1))) unsigned int*)g,
                                   (__attribute__((address_space(3))) unsigned int*)lds,
                                   16, 0, 0);
}

template<int EPI, int CIRC>
__global__ __launch_bounds__(256) void gemm_bt(
    const unsigned short* __restrict__ A, const unsigned short* __restrict__ Bw,
    const float* __restrict__ bias, unsigned short* __restrict__ Cb,
    int M, int N, int K, int L, int Lsh, size_t qkvs, int NBN, int xswz)
{
  __shared__ unsigned short sA[128 * 64];
  __shared__ unsigned short sB[128 * 64];
  const int tid = threadIdx.x;
  const int wave = tid >> 6, lane = tid & 63;

  int blk = blockIdx.x;
  if (xswz) { int cpx = (int)gridDim.x >> 3; blk = (blk & 7) * cpx + (blk >> 3); }
  const int bn = blk % NBN, bm = blk / NBN;

  const int wm = (wave >> 1) << 6, wn = (wave & 1) << 6;

  const int srow = (wave << 5) + (lane >> 3);
  const int kb = (((lane & 7) ^ ((lane >> 3) & 7)) << 3);

  const unsigned short* gA = nullptr;
  int lI = 0;
  if constexpr (CIRC) {
    int r = bm * 128 + srow;
    lI = r & (L - 1);
  } else {
    gA = A + (size_t)(bm * 128 + srow) * K + kb;
  }
  const unsigned short* gB = Bw + (size_t)(bn * 128 + srow) * K + kb;

  f32x4 acc[4][4] = {};

  for (int k0 = 0; k0 < K; k0 += 64) {
#pragma unroll
    for (int q = 0; q < 4; q++) {
      unsigned short* ldsA = &sA[((wave << 5) + (q << 3)) << 6];
      unsigned short* ldsB = &sB[((wave << 5) + (q << 3)) << 6];
      if constexpr (CIRC) {
        int t = k0 >> 9;
        int kk = (k0 & 511) + kb;
        int sl = (lI + (q << 3) - 1 + t + L) & (L - 1);
        int bq = (bm * 128 + srow + (q << 3)) >> Lsh;
        async_copy16(ldsA, A + (((size_t)(bq * L + sl)) << 9) + kk);
      } else {
        async_copy16(ldsA, gA + (size_t)(q << 3) * K + k0);
      }
      async_copy16(ldsB, gB + (size_t)(q << 3) * K + k0);
    }
    __syncthreads();
#pragma unroll
    for (int kk = 0; kk < 2; kk++) {
      bf16x8 af[4], bfr[4];
#pragma unroll
      for (int i = 0; i < 4; i++) {
        int row = wm + (i << 4) + (lane & 15);
        int slot = ((kk << 2) + (lane >> 4)) ^ (lane & 7);
        af[i] = *(const bf16x8*)&sA[(row << 6) + (slot << 3)];
      }
#pragma unroll
      for (int j = 0; j < 4; j++) {
        int row = wn + (j << 4) + (lane & 15);
        int slot = ((kk << 2) + (lane >> 4)) ^ (lane & 7);
        bfr[j] = *(const bf16x8*)&sB[(row << 6) + (slot << 3)];
      }
#pragma unroll
      for (int i = 0; i < 4; i++)
#pragma unroll
        for (int j = 0; j < 4; j++)
          acc[i][j] = __builtin_amdgcn_mfma_f32_16x16x32_bf16(af[i], bfr[j], acc[i][j], 0, 0, 0);
    }
    __syncthreads();
  }

  // ---- epilogue: LDS repack, coalesced stores (fully unrolled) ----
  unsigned short* sOut = sA;                 // 32 rows x stride 136
  const int cr = (lane >> 4) << 2;
  const int cc = lane & 15;
  const int lrb = ((wave >> 1) << 4) + cr;
  const int lr = tid >> 3, ch0 = tid & 7;
#pragma unroll
  for (int i = 0; i < 4; i++) {
    if (i) __syncthreads();
#pragma unroll
    for (int j = 0; j < 4; j++) {
      const int col = wn + (j << 4) + cc;
      const float bvv = bias[(bn << 7) + col];
#pragma unroll
      for (int r = 0; r < 4; r++) {
        float v = acc[i][j][r] + bvv;
        if constexpr (EPI == 2) {
          v = 0.5f * v * (1.0f + erff(v * 0.70710678118654752f));
        }
        sOut[(lrb + r) * 136 + col] = f2bf(v);
      }
    }
    __syncthreads();
    int grow = (bm << 7) + ((lr >> 4) << 6) + (i << 4) + (lr & 15);
#pragma unroll
    for (int cpart = 0; cpart < 2; cpart++) {
      int ch = ch0 + (cpart << 3);
      uint4 val = *(const uint4*)&sOut[lr * 136 + (ch << 3)];
      if constexpr (EPI == 3) {
        int gcol = (bn << 7) + (ch << 3);
        *(uint4*)&Cb[(size_t)(gcol >> 9) * qkvs + ((size_t)grow << 9) + (gcol & 511)] = val;
      } else {
        *(uint4*)&Cb[(size_t)grow * N + (bn << 7) + (ch << 3)] = val;
      }
    }
  }
}

// ---------------- embedding circular conv (C=7, W=3) -> bf16 ---------------
__global__ __launch_bounds__(256) void embed_kernel(const float* __restrict__ xe,
    const float* __restrict__ w, unsigned short* __restrict__ xb)
{
  int blk = blockIdx.x;             // nb * 64
  int b = blk >> 6, lg = blk & 63;
  int l0 = lg << 5;
  int tid = threadIdx.x;
  __shared__ float xwin[34 * 7];
  for (int i = tid; i < 34 * 7; i += 256) {
    int r = i / 7, c = i - r * 7;
    int sl = (l0 - 1 + r) & 2047;
    xwin[i] = xe[((size_t)(b * 2048 + sl)) * 7 + c];
  }
  __syncthreads();
  float wr0[21], wr1[21];
  const float* w0 = w + tid * 21;
  const float* w1 = w + (tid + 256) * 21;
#pragma unroll
  for (int k = 0; k < 21; k++) { wr0[k] = w0[k]; wr1[k] = w1[k]; }
#pragma unroll 1
  for (int ll = 0; ll < 32; ll++) {
    float a0 = 0.0f, a1 = 0.0f;
#pragma unroll
    for (int c = 0; c < 7; c++)
#pragma unroll
      for (int t = 0; t < 3; t++) {
        float xv = xwin[(ll + t) * 7 + c];
        a0 += xv * wr0[c * 3 + t];
        a1 += xv * wr1[c * 3 + t];
      }
    size_t o = ((size_t)(b * 2048 + l0 + ll)) << 9;
    xb[o + tid] = f2bf(a0);
    xb[o + 256 + tid] = f2bf(a1);
  }
}

// ---------------- M = max_j(qk_samp) - sum_j(qk_samp)/L --------------------
template<int U>
__global__ __launch_bounds__(256) void msamp_kernel(
    const unsigned short* __restrict__ qb, const unsigned short* __restrict__ kbuf,
    const int* __restrict__ idx, float* __restrict__ Mv, int L, int nlc, float invL,
    int xcdgrp)
{
  const int RB = 16;
  int blk = blockIdx.x;
  int b, lc;
  if (xcdgrp) {
    int xcd = blk & 7, slot = blk >> 3;
    int g = slot / nlc; lc = slot - g * nlc;
    b = g * 8 + xcd;
  } else {
    b = blk / nlc; lc = blk - b * nlc;
  }
  int l0 = lc * RB;
  int tid = threadIdx.x;
  int wave = tid >> 6, lane = tid & 63;
  int p = lane & 7, h = lane >> 3;
  __shared__ int iidx[RB * U];
  __shared__ float pM[RB * 8 * 25];

  for (int i = tid; i < RB * U; i += 256) iidx[i] = idx[l0 * U + i];
  __syncthreads();

  const size_t rowbase = ((size_t)(b * L)) << 9;
#pragma unroll
  for (int r = 0; r < RB / 4; r++) {
    int l = wave * (RB / 4) + r;
    uint4 qv = *(const uint4*)(qb + rowbase + (((size_t)(l0 + l)) << 9) + (lane << 3));
    float qf[8]; unpack8(qv, qf);
    int kr[U];
#pragma unroll
    for (int j = 0; j < U; j++) kr[j] = iidx[l * U + j];
#pragma unroll
    for (int j = 0; j < U; j++) {
      uint4 kv = *(const uint4*)(kbuf + rowbase + (((size_t)kr[j]) << 9) + (lane << 3));
      float s = dot8(kv, qf);
      s += __shfl_xor(s, 1);
      s += __shfl_xor(s, 2);
      s += __shfl_xor(s, 4);
      if (p == 0) pM[(l * 8 + h) * 25 + j] = s;
    }
  }
  __syncthreads();

  if (tid < RB * 8) {
    int l = tid >> 3, hh = tid & 7;
    float mx = -3.0e38f, sm = 0.0f;
    const float* pr = &pM[tid * 25];
    for (int j = 0; j < U; j++) { float v = pr[j]; mx = fmaxf(mx, v); sm += v; }
    Mv[((size_t)((b << 3) + hh)) * L + l0 + l] = mx - sm * invL;
  }
}

// ---------------- top-u: register-resident, shuffle-reduce -----------------
template<int S>
__global__ __launch_bounds__(256) void topk_kernel(const float* __restrict__ Mv,
    int* __restrict__ mtop, int L, int u)
{
  int bh = blockIdx.x; int tid = threadIdx.x;
  int wave = tid >> 6, lane = tid & 63;
  float lv[S];
#pragma unroll
  for (int s = 0; s < S; s++) lv[s] = Mv[(size_t)bh * L + s * 256 + tid];
  __shared__ float sv[4];
  __shared__ int si[4];
  for (int t = 0; t < u; t++) {
    float bv = lv[0]; int bs = 0;
#pragma unroll
    for (int s = 1; s < S; s++) if (lv[s] > bv) { bv = lv[s]; bs = s; }
    int bi = bs * 256 + tid;
#pragma unroll
    for (int o = 1; o < 64; o <<= 1) {
      float ov = __shfl_xor(bv, o); int oi = __shfl_xor(bi, o);
      if (ov > bv || (ov == bv && oi < bi)) { bv = ov; bi = oi; }
    }
    if (lane == 0) { sv[wave] = bv; si[wave] = bi; }
    __syncthreads();
    float wv = sv[0]; int wi = si[0];
#pragma unroll
    for (int w = 1; w < 4; w++) {
      float ov = sv[w]; int oi = si[w];
      if (ov > wv || (ov == wv && oi < wi)) { wv = ov; wi = oi; }
    }
    if (tid == 0) mtop[bh * u + t] = wi;
#pragma unroll
    for (int s = 0; s < S; s++)
      if (s == (wi >> 8) && (wi & 255) == tid) lv[s] = -3.0e38f;
    __syncthreads();
  }
}

// ---------------- attention part: one 256-row K/V chunk per block ----------
// LDS: pA (exp matrix) and pB (partial-update staging) have disjoint
// lifetimes -> unioned in one arena (57.5KB -> 32.9KB, 2 -> 4 blocks/CU).
template<int U>
__device__ __forceinline__ void dot_rows(const unsigned short* __restrict__ krow,
                                         const float* __restrict__ qred, float* s)
{
#pragma unroll
  for (int j = 0; j < U; j++) s[j] = 0.0f;
  const uint4* kv4 = (const uint4*)krow;
#pragma unroll
  for (int d8 = 0; d8 < 8; d8++) {
    uint4 kv = kv4[d8];
    float kf[8];
    kf[0] = bf2f((unsigned short)(kv.x & 0xffff)); kf[1] = bf2f((unsigned short)(kv.x >> 16));
    kf[2] = bf2f((unsigned short)(kv.y & 0xffff)); kf[3] = bf2f((unsigned short)(kv.y >> 16));
    kf[4] = bf2f((unsigned short)(kv.z & 0xffff)); kf[5] = bf2f((unsigned short)(kv.z >> 16));
    kf[6] = bf2f((unsigned short)(kv.w & 0xffff)); kf[7] = bf2f((unsigned short)(kv.w >> 16));
#pragma unroll
    for (int j = 0; j < U; j++) {
      const float4 q0 = *(const float4*)&qred[j * 64 + d8 * 8];
      const float4 q1 = *(const float4*)&qred[j * 64 + d8 * 8 + 4];
      s[j] += kf[0] * q0.x + kf[1] * q0.y + kf[2] * q0.z + kf[3] * q0.w
            + kf[4] * q1.x + kf[5] * q1.y + kf[6] * q1.z + kf[7] * q1.w;
    }
  }
}

template<int U>
__global__ __launch_bounds__(256) void attn_part(
    const unsigned short* __restrict__ qb, const unsigned short* __restrict__ kbuf,
    const unsigned short* __restrict__ vbuf, const int* __restrict__ mtop,
    float* __restrict__ pupd, float* __restrict__ pden, float* __restrict__ pvs,
    int L, int S)
{
  int blk = blockIdx.x;
  int bh = blk / S, split = blk - bh * S;
  int b = bh >> 3, h = bh & 7;
  int tid = threadIdx.x;
  __shared__ float qred[U * 64];
  __shared__ float arena[U * 4 * 66];   // pA during exp+V pass; pB after
  __shared__ float pC[256];
  __shared__ float dnred[4 * U];
  float* pA = arena;
  float* pB = arena;                    // alias: pA dead before pB born

  for (int i = tid; i < U * 64; i += 256) {
    int j = i >> 6, d = i & 63;
    int row = mtop[bh * U + j];
    qred[i] = bf2f(qb[(((size_t)(b * L + row)) << 9) + h * 64 + d]) * 0.125f;
  }
  __syncthreads();

  int l = (split << 8) + tid;
  {
    float s[U];
    dot_rows<U>(kbuf + (((size_t)(b * L + l)) << 9) + h * 64, qred, s);
    int g0 = tid >> 6, d0 = tid & 63;
#pragma unroll
    for (int j = 0; j < U; j++) pA[(j * 4 + g0) * 66 + d0] = expf(s[j]);
  }
  __syncthreads();

  int g = tid >> 6, d = tid & 63;
  const unsigned short* vcol = vbuf + (((size_t)(b * L)) << 9) + h * 64 + d;
  float lupd[U], ldn[U]; float lvs = 0.0f;
#pragma unroll
  for (int j = 0; j < U; j++) { lupd[j] = 0.0f; ldn[j] = 0.0f; }
#pragma unroll 1
  for (int li = 0; li < 64; li++) {
    int ll = (split << 8) + (g << 6) + li;
    float vd = bf2f(vcol[(size_t)ll << 9]);
    lvs += vd;
#pragma unroll
    for (int j = 0; j < U; j++) {
      float pv = pA[(j * 4 + g) * 66 + li];
      ldn[j] += pv; lupd[j] += pv * vd;
    }
  }
  if (d == 0) {
#pragma unroll
    for (int j = 0; j < U; j++) dnred[g * U + j] = ldn[j];
  }
  pC[tid] = lvs;
  __syncthreads();              // all waves done reading pA
#pragma unroll
  for (int j = 0; j < U; j++) pB[(g * U + j) * 64 + d] = lupd[j];
  __syncthreads();

  size_t base = (size_t)bh * S + split;
  for (int i = tid; i < U * 64; i += 256) {
    int j = i >> 6, dd = i & 63;
    pupd[base * (U * 64) + i] = pB[j * 64 + dd] + pB[(U + j) * 64 + dd]
                              + pB[(2 * U + j) * 64 + dd] + pB[(3 * U + j) * 64 + dd];
  }
  if (tid < U)
    pden[base * U + tid] = dnred[tid] + dnred[U + tid] + dnred[2 * U + tid] + dnred[3 * U + tid];
  if (tid < 64)
    pvs[base * 64 + tid] = pC[tid] + pC[64 + tid] + pC[128 + tid] + pC[192 + tid];
}

// ---------------- attention combine: vmean bcast + top-row scatter ---------
template<int U>
__global__ __launch_bounds__(256) void attn_comb(
    const int* __restrict__ mtop, const float* __restrict__ pupd,
    const float* __restrict__ pden, const float* __restrict__ pvs,
    unsigned short* __restrict__ ab, int L, int S)
{
  int bh = blockIdx.x; int b = bh >> 3, h = bh & 7;
  int tid = threadIdx.x;
  __shared__ float updf[U * 64];
  __shared__ float den[U];
  __shared__ float vm[64];
  for (int i = tid; i < U * 64; i += 256) {
    float s = 0.0f;
    for (int sp = 0; sp < S; sp++) s += pupd[((size_t)bh * S + sp) * (U * 64) + i];
    updf[i] = s;
  }
  if (tid < U) {
    float s = 0.0f;
    for (int sp = 0; sp < S; sp++) s += pden[((size_t)bh * S + sp) * U + tid];
    den[tid] = s;
  }
  if (tid < 64) {
    float s = 0.0f;
    for (int sp = 0; sp < S; sp++) s += pvs[((size_t)bh * S + sp) * 64 + tid];
    vm[tid] = s / (float)L;
  }
  __syncthreads();
  int g = tid >> 6, d = tid & 63;
  unsigned short vmb = f2bf(vm[d]);
  for (int l = g; l < L; l += 4)
    ab[(((size_t)(b * L + l)) << 9) + h * 64 + d] = vmb;
  __syncthreads();
  for (int i = tid; i < U * 64; i += 256) {
    int j = i >> 6, dd = i & 63;
    int row = mtop[bh * U + j];
    ab[(((size_t)(b * L + row)) << 9) + h * 64 + dd] = f2bf(updf[i] / den[j]);
  }
}

// ---------------- layernorm, 512 cols; bf16 in/resid; bf16/f32 out ---------
__global__ __launch_bounds__(256) void ln_kernel(const unsigned short* __restrict__ xinb,
    const unsigned short* __restrict__ residb, const float* __restrict__ g,
    const float* __restrict__ beta, unsigned short* __restrict__ xbout,
    float* __restrict__ xfout)
{
  size_t base = (size_t)blockIdx.x * 512; int tid = threadIdx.x;
  float v0 = 0.0f, v1 = 0.0f;
  if (xinb)   { v0 += bf2f(xinb[base + tid]); v1 += bf2f(xinb[base + 256 + tid]); }
  if (residb) { v0 += bf2f(residb[base + tid]); v1 += bf2f(residb[base + 256 + tid]); }
  __shared__ float red[256];
  __shared__ float smean, srstd;
  red[tid] = v0 + v1; __syncthreads();
  for (int s = 128; s > 0; s >>= 1) { if (tid < s) red[tid] += red[tid + s]; __syncthreads(); }
  if (tid == 0) smean = red[0] * (1.0f / 512.0f);
  __syncthreads();
  float m = smean;
  float d0 = v0 - m, d1 = v1 - m;
  red[tid] = d0 * d0 + d1 * d1; __syncthreads();
  for (int s = 128; s > 0; s >>= 1) { if (tid < s) red[tid] += red[tid + s]; __syncthreads(); }
  if (tid == 0) srstd = rsqrtf(red[0] * (1.0f / 512.0f) + 1e-5f);
  __syncthreads();
  float rs = srstd;
  float o0 = d0 * rs * g[tid] + beta[tid];
  float o1 = d1 * rs * g[tid + 256] + beta[tid + 256];
  if (xbout) { xbout[base + tid] = f2bf(o0); xbout[base + 256 + tid] = f2bf(o1); }
  if (xfout) { xfout[base + tid] = o0; xfout[base + 256 + tid] = o1; }
}

// ---------------- distil pool: bn-scale, elu, maxpool(3,2,pad1), bf16 in ---
__global__ void pool_kernel(const unsigned short* __restrict__ z, const float* __restrict__ g,
    const float* __restrict__ beta, unsigned short* __restrict__ xbout, int L, int count)
{
  int i = blockIdx.x * 256 + threadIdx.x;
  if (i >= count) return;
  int o = i & 511; int r1 = i >> 9;
  int Lh = L >> 1;
  int l2 = r1 % Lh; int b = r1 / Lh;
  const float invs = 0.99999500003749969f;
  float gg = g[o] * invs, bb = beta[o];
  float m = -3.0e38f;
#pragma unroll
  for (int w = -1; w <= 1; w++) {
    int l = 2 * l2 + w;
    if (l >= 0 && l < L) {
      float y = bf2f(z[(size_t)(b * L + l) * DM + o]) * gg + bb;
      y = (y > 0.0f) ? y : expm1f(y);
      m = fmaxf(m, y);
    }
  }
  xbout[(size_t)(b * Lh + l2) * DM + o] = f2bf(m);
}

// ---------------- misc ------------------------------------------------------
__global__ void cvt_kernel(const float* __restrict__ in, unsigned short* __restrict__ out, int n) {
  int i = blockIdx.x * 256 + threadIdx.x;
  if (i < n) out[i] = f2bf(in[i]);
}

__global__ void cvt_qkv(const float* __restrict__ src, unsigned short* __restrict__ dst, int matoff) {
  int i = blockIdx.x * 256 + threadIdx.x;
  if (i >= 786432) return;
  int layer = i >> 18; int rem = i & 262143;
  dst[(size_t)layer * 786432 + matoff + rem] = f2bf(src[i]);
}

__global__ void catbias(const float* __restrict__ bq, const float* __restrict__ bk,
                        const float* __restrict__ bv, float* __restrict__ dst) {
  int i = blockIdx.x * 256 + threadIdx.x;
  if (i >= 3 * 1536) return;
  int layer = i / 1536, c = i - layer * 1536;
  float v = (c < 512) ? bq[layer * 512 + c]
          : (c < 1024) ? bk[layer * 512 + c - 512]
          : bv[layer * 512 + c - 1024];
  dst[i] = v;
}

__global__ void repack_dcw(const float* __restrict__ dcw, unsigned short* __restrict__ wt, int n) {
  int i = blockIdx.x * 256 + threadIdx.x;
  if (i >= n) return;
  int t = i % 3; int rest = i / 3; int c = rest % 512; int lo = rest / 512;
  wt[(size_t)lo * 1536 + t * 512 + c] = f2bf(dcw[i]);
}

// ---- 2-stage deterministic mean over L=512 rows (f32 input) ----
__global__ void mean_part(const float* __restrict__ xin, float* __restrict__ part, int nblkPerB) {
  int blk = blockIdx.x;
  int b = blk / nblkPerB, pc = blk - b * nblkPerB;
  int tid = threadIdx.x;
  float s0 = 0.0f, s1 = 0.0f;
  int l0 = pc * 32;
  for (int r = 0; r < 32; r++) {
    size_t base = ((size_t)(b * 512 + l0 + r)) << 9;
    s0 += xin[base + tid];
    s1 += xin[base + 256 + tid];
  }
  part[((size_t)blk << 9) + tid] = s0;
  part[((size_t)blk << 9) + 256 + tid] = s1;
}
__global__ void mean_fin(const float* __restrict__ part, float* __restrict__ out,
                         int nblkPerB, int nb) {
  int i = blockIdx.x * 256 + threadIdx.x;
  if (i >= nb * 512) return;
  int b = i >> 9, d = i & 511;
  float s = 0.0f;
  for (int c = 0; c < nblkPerB; c++) s += part[((size_t)(b * nblkPerB + c) << 9) + d];
  out[i] = s * (1.0f / 512.0f);
}

// ---------------- host ------------------------------------------------------
extern "C" void kernel_launch(void* const* d_in, const int* in_sizes, int n_in,
                              void* d_out, int out_size, void* d_ws, size_t ws_size,
                              hipStream_t stream)
{
  (void)in_sizes; (void)n_in; (void)out_size;
  const float* x_enc = (const float*)d_in[0];
  const float* emb_w = (const float*)d_in[1];
  const float* wq   = (const float*)d_in[2];
  const float* bq   = (const float*)d_in[3];
  const float* wk   = (const float*)d_in[4];
  const float* bk   = (const float*)d_in[5];
  const float* wv   = (const float*)d_in[6];
  const float* bvv  = (const float*)d_in[7];
  const float* wo   = (const float*)d_in[8];
  const float* bo   = (const float*)d_in[9];
  const float* c1w  = (const float*)d_in[10];
  const float* c1b  = (const float*)d_in[11];
  const float* c2w  = (const float*)d_in[12];
  const float* c2b  = (const float*)d_in[13];
  const float* ln1g = (const float*)d_in[14];
  const float* ln1b = (const float*)d_in[15];
  const float* ln2g = (const float*)d_in[16];
  const float* ln2b = (const float*)d_in[17];
  const float* dcw  = (const float*)d_in[18];
  const float* dcb  = (const float*)d_in[19];
  const float* bng  = (const float*)d_in[20];
  const float* bnb  = (const float*)d_in[21];
  const float* lnfg = (const float*)d_in[22];
  const float* lnfb = (const float*)d_in[23];

  // ---- choose batch-chunk size: need = 16MB + nb*8.8MB ----
  int nb = 32;
  while (nb > 1 && (16777216ull + (size_t)nb * 8804352ull) > ws_size) nb >>= 1;

  // ---- fixed small region (first 16MB) ----
  char* ws = (char*)d_ws;
  size_t off = 0;
  unsigned short* WQKV = (unsigned short*)(ws + off); off += 4718592ull;
  unsigned short* WOB  = (unsigned short*)(ws + off); off += 1572864ull;
  unsigned short* C1WB = (unsigned short*)(ws + off); off += 1572864ull;
  unsigned short* C2WB = (unsigned short*)(ws + off); off += 1572864ull;
  unsigned short* WTB  = (unsigned short*)(ws + off); off += 3145728ull;
  float* BQKVB         = (float*)(ws + off);          off += 18432ull;
  float* MP            = (float*)(ws + off);          off += 2097152ull;
  int* IDXP            = (int*)(ws + off);            off += 589824ull;
  int* MTOPP           = (int*)(ws + off);            off += 24576ull;

  // ---- chunk region ----
  size_t cb = 16777216ull;
  unsigned short* Xbf  = (unsigned short*)(ws + cb);
  char* R              = ws + cb + (size_t)nb * 2097152ull;
  unsigned short* DQ   = (unsigned short*)R;
  unsigned short* DK   = (unsigned short*)(R + (size_t)nb * 2097152ull);
  unsigned short* DV   = (unsigned short*)(R + (size_t)nb * 4194304ull);
  unsigned short* TMPB = DQ;                             // bf16 GEMM out (Q dead)
  float* TMPF          = (float*)DK;                     // final-LN f32 (K dead)
  unsigned short* AB   = DV;                             // ctx/ffn-mid (V dead)
  float* PUPD          = (float*)(ws + cb + (size_t)nb * 8388608ull);
  float* PDEN          = (float*)((char*)PUPD + (size_t)nb * 393216ull);
  float* PVS           = (float*)((char*)PDEN + (size_t)nb * 6144ull);
  const size_t qkvs    = (size_t)nb * 1048576ull;

  // ---- weights to bf16 (once) ----
  {
    int nw = 3 * 512 * 512;
    int blocks = (nw + 255) / 256;
    cvt_qkv<<<blocks, 256, 0, stream>>>(wq, WQKV, 0);
    cvt_qkv<<<blocks, 256, 0, stream>>>(wk, WQKV, 262144);
    cvt_qkv<<<blocks, 256, 0, stream>>>(wv, WQKV, 524288);
    catbias<<<18, 256, 0, stream>>>(bq, bk, bvv, BQKVB);
    cvt_kernel<<<blocks, 256, 0, stream>>>(wo,  WOB,  nw);
    cvt_kernel<<<blocks, 256, 0, stream>>>(c1w, C1WB, nw);
    cvt_kernel<<<blocks, 256, 0, stream>>>(c2w, C2WB, nw);
    int nd = 2 * 512 * 512 * 3;
    repack_dcw<<<(nd + 255) / 256, 256, 0, stream>>>(dcw, WTB, nd);
  }

  // ---- sample indices per layer (once) ----
  for (int layer = 0; layer < 3; layer++) {
    int Ll = (layer == 0) ? 2048 : (layer == 1 ? 1024 : 512);
    int ul = (layer == 0) ? 24 : 21;
    uint32_t f0, f1, a0, b0k, a1, b1k;
    tf2x32(0u, 42u, 0u, (uint32_t)layer, &f0, &f1);
    tf2x32(f0, f1, 0u, 2u, &a0, &b0k);
    tf2x32(f0, f1, 1u, 3u, &a1, &b1k);
    (void)a0; (void)a1;
    int nhalf = Ll * ul / 2;
    idx_kernel<<<(nhalf + 255) / 256, 256, 0, stream>>>(IDXP + layer * 49152, nhalf, b0k, b1k, Ll - 1);
  }

  // ---- per-chunk full pipeline ----
  for (int b0 = 0; b0 < 32; b0 += nb) {
    embed_kernel<<<nb * 64, 256, 0, stream>>>(x_enc + (size_t)b0 * 2048 * 7, emb_w, Xbf);

    int L = 2048, Lsh = 11;
    for (int layer = 0; layer < 3; layer++) {
      const int M_ = nb * L;
      const int u = (layer == 0) ? 24 : 21;
      const int S = L >> 8;
      const int nbm = M_ / 128;
      const int ng  = 4 * nbm;
      const int ngq = 12 * nbm;
      const int xsg  = (ng  % 8 == 0) ? 1 : 0;
      const int xsgq = (ngq % 8 == 0) ? 1 : 0;
      const int xg = (nb % 8 == 0) ? 1 : 0;

      gemm_bt<3,0><<<ngq, 256, 0, stream>>>(Xbf, WQKV + (size_t)layer * 786432, BQKVB + layer * 1536, DQ, M_, 1536, 512, 0, 0, qkvs, 12, xsgq);

      if (u == 24) msamp_kernel<24><<<nb * (L / 16), 256, 0, stream>>>(DQ, DK, IDXP + layer * 49152, MP, L, L / 16, 1.0f / (float)L, xg);
      else         msamp_kernel<21><<<nb * (L / 16), 256, 0, stream>>>(DQ, DK, IDXP + layer * 49152, MP, L, L / 16, 1.0f / (float)L, xg);

      if (L == 2048)      topk_kernel<8><<<nb * 8, 256, 0, stream>>>(MP, MTOPP, L, u);
      else if (L == 1024) topk_kernel<4><<<nb * 8, 256, 0, stream>>>(MP, MTOPP, L, u);
      else                topk_kernel<2><<<nb * 8, 256, 0, stream>>>(MP, MTOPP, L, u);

      if (u == 24) {
        attn_part<24><<<nb * 8 * S, 256, 0, stream>>>(DQ, DK, DV, MTOPP, PUPD, PDEN, PVS, L, S);
        attn_comb<24><<<nb * 8, 256, 0, stream>>>(MTOPP, PUPD, PDEN, PVS, AB, L, S);
      } else {
        attn_part<21><<<nb * 8 * S, 256, 0, stream>>>(DQ, DK, DV, MTOPP, PUPD, PDEN, PVS, L, S);
        attn_comb<21><<<nb * 8, 256, 0, stream>>>(MTOPP, PUPD, PDEN, PVS, AB, L, S);
      }

      // Q/K/V dead; TMPB (=DQ) live from here.
      gemm_bt<1,0><<<ng, 256, 0, stream>>>(AB, WOB + (size_t)layer * 262144, bo + layer * 512, TMPB, M_, 512, 512, 0, 0, 0, 4, xsg);
      ln_kernel<<<M_, 256, 0, stream>>>(TMPB, Xbf, ln1g + layer * 512, ln1b + layer * 512, Xbf, nullptr);
      gemm_bt<2,0><<<ng, 256, 0, stream>>>(Xbf, C1WB + (size_t)layer * 262144, c1b + layer * 512, AB, M_, 512, 512, 0, 0, 0, 4, xsg);
      gemm_bt<1,0><<<ng, 256, 0, stream>>>(AB, C2WB + (size_t)layer * 262144, c2b + layer * 512, TMPB, M_, 512, 512, 0, 0, 0, 4, xsg);
      ln_kernel<<<M_, 256, 0, stream>>>(TMPB, Xbf, ln2g + layer * 512, ln2b + layer * 512, Xbf, nullptr);

      if (layer < 2) {
        gemm_bt<1,1><<<ng, 256, 0, stream>>>(Xbf, WTB + (size_t)layer * 786432, dcb + layer * 512, TMPB, M_, 512, 1536, L, Lsh, 0, 4, xsg);
        pool_kernel<<<nb * L, 256, 0, stream>>>(TMPB, bng + layer * 512, bnb + layer * 512, Xbf, L, nb * (L / 2) * 512);
        L >>= 1; Lsh -= 1;
      }
    }

    ln_kernel<<<nb * 512, 256, 0, stream>>>(nullptr, Xbf, lnfg, lnfb, nullptr, TMPF);
    mean_part<<<nb * 16, 256, 0, stream>>>(TMPF, MP, 16);
    mean_fin<<<(nb * 512 + 255) / 256, 256, 0, stream>>>(MP, (float*)d_out + (size_t)b0 * 512, 16, nb);
  }
}

// Round 17
// 2149.262 us; speedup vs baseline: 3.3825x; 1.0103x over previous
//
#include <hip/hip_runtime.h>
#include <stdint.h>

#define DM 512
#define DH 64

typedef __bf16 bf16x8 __attribute__((ext_vector_type(8)));
typedef float f32x4 __attribute__((ext_vector_type(4)));

__device__ __forceinline__ float bf2f(unsigned short h) {
  union { unsigned int u; float f; } c; c.u = ((unsigned int)h) << 16; return c.f;
}
__device__ __forceinline__ unsigned short f2bf(float f) {
  union { float f; unsigned int u; } c; c.f = f;
  unsigned int u = c.u;
  return (unsigned short)((u + 0x7FFFu + ((u >> 16) & 1u)) >> 16);
}
__device__ __forceinline__ void unpack8(uint4 v, float* f) {
  f[0] = bf2f((unsigned short)(v.x & 0xffff)); f[1] = bf2f((unsigned short)(v.x >> 16));
  f[2] = bf2f((unsigned short)(v.y & 0xffff)); f[3] = bf2f((unsigned short)(v.y >> 16));
  f[4] = bf2f((unsigned short)(v.z & 0xffff)); f[5] = bf2f((unsigned short)(v.z >> 16));
  f[6] = bf2f((unsigned short)(v.w & 0xffff)); f[7] = bf2f((unsigned short)(v.w >> 16));
}
__device__ __forceinline__ float dot8(uint4 kv, const float* qf) {
  float s;
  s  = bf2f((unsigned short)(kv.x & 0xffff)) * qf[0];
  s += bf2f((unsigned short)(kv.x >> 16))    * qf[1];
  s += bf2f((unsigned short)(kv.y & 0xffff)) * qf[2];
  s += bf2f((unsigned short)(kv.y >> 16))    * qf[3];
  s += bf2f((unsigned short)(kv.z & 0xffff)) * qf[4];
  s += bf2f((unsigned short)(kv.z >> 16))    * qf[5];
  s += bf2f((unsigned short)(kv.w & 0xffff)) * qf[6];
  s += bf2f((unsigned short)(kv.w >> 16))    * qf[7];
  return s;
}

// ---------------- Threefry-2x32 (20 rounds), JAX-compatible ----------------
__host__ __device__ inline void tf2x32(uint32_t k0, uint32_t k1, uint32_t x0, uint32_t x1,
                                       uint32_t* o0, uint32_t* o1) {
  uint32_t ks2 = k0 ^ k1 ^ 0x1BD11BDAu;
#define TFR(r) { x0 += x1; x1 = (x1 << r) | (x1 >> (32 - r)); x1 ^= x0; }
  x0 += k0; x1 += k1;
  TFR(13) TFR(15) TFR(26) TFR(6)
  x0 += k1; x1 += ks2 + 1u;
  TFR(17) TFR(29) TFR(16) TFR(24)
  x0 += ks2; x1 += k0 + 2u;
  TFR(13) TFR(15) TFR(26) TFR(6)
  x0 += k0; x1 += k1 + 3u;
  TFR(17) TFR(29) TFR(16) TFR(24)
  x0 += k1; x1 += ks2 + 4u;
  TFR(13) TFR(15) TFR(26) TFR(6)
  *o0 = x0 + ks2; *o1 = x1 + k0 + 5u;
#undef TFR
}

__global__ void idx_kernel(int* __restrict__ idx, int nhalf, unsigned int k0, unsigned int k1, int mask) {
  int m = blockIdx.x * 256 + threadIdx.x;
  if (m >= nhalf) return;
  uint32_t o0, o1;
  tf2x32(k0, k1, (uint32_t)m, (uint32_t)(m + nhalf), &o0, &o1);
  idx[m] = (int)(o0 & (uint32_t)mask);
  idx[m + nhalf] = (int)(o1 & (uint32_t)mask);
}

// ---------------- bf16 GEMM: C(M,N) = A(M,K) * B(N,K)^T + bias -------------
// 1D grid, XCD-bijective swizzle; bn = wgid % NBN (fast), bm = wgid / NBN.
// BK=64 (8 K-iters at K=512); XOR-swizzled LDS via pre-swizzled global src.
// Epilogue: fully unrolled (rule #20); LDS-repacked coalesced 16B stores.
// EPI: 1 = bf16; 2 = gelu->bf16; 3 = bf16 QKV-split (col>>9 selects Q/K/V).
// CIRC: logical A row m, col k -> A[b*L + ((l-1+t) mod L)][k%512], t=k/512.
__device__ __forceinline__ void async_copy16(void* lds, const void* g) {
  __builtin_amdgcn_global_load_lds((const __attribute__((address_space(1))) unsigned int*)g,
                                   (__attribute__((address_space(3))) unsigned int*)lds,
                                   16, 0, 0);
}

template<int EPI, int CIRC>
__global__ __launch_bounds__(256) void gemm_bt(
    const unsigned short* __restrict__ A, const unsigned short* __restrict__ Bw,
    const float* __restrict__ bias, unsigned short* __restrict__ Cb,
    int M, int N, int K, int L, int Lsh, size_t qkvs, int NBN, int xswz)
{
  __shared__ unsigned short sA[128 * 64];
  __shared__ unsigned short sB[128 * 64];
  const int tid = threadIdx.x;
  const int wave = tid >> 6, lane = tid & 63;

  int blk = blockIdx.x;
  if (xswz) { int cpx = (int)gridDim.x >> 3; blk = (blk & 7) * cpx + (blk >> 3); }
  const int bn = blk % NBN, bm = blk / NBN;

  const int wm = (wave >> 1) << 6, wn = (wave & 1) << 6;

  const int srow = (wave << 5) + (lane >> 3);
  const int kb = (((lane & 7) ^ ((lane >> 3) & 7)) << 3);

  const unsigned short* gA = nullptr;
  int lI = 0;
  if constexpr (CIRC) {
    int r = bm * 128 + srow;
    lI = r & (L - 1);
  } else {
    gA = A + (size_t)(bm * 128 + srow) * K + kb;
  }
  const unsigned short* gB = Bw + (size_t)(bn * 128 + srow) * K + kb;

  f32x4 acc[4][4] = {};

  for (int k0 = 0; k0 < K; k0 += 64) {
#pragma unroll
    for (int q = 0; q < 4; q++) {
      unsigned short* ldsA = &sA[((wave << 5) + (q << 3)) << 6];
      unsigned short* ldsB = &sB[((wave << 5) + (q << 3)) << 6];
      if constexpr (CIRC) {
        int t = k0 >> 9;
        int kk = (k0 & 511) + kb;
        int sl = (lI + (q << 3) - 1 + t + L) & (L - 1);
        int bq = (bm * 128 + srow + (q << 3)) >> Lsh;
        async_copy16(ldsA, A + (((size_t)(bq * L + sl)) << 9) + kk);
      } else {
        async_copy16(ldsA, gA + (size_t)(q << 3) * K + k0);
      }
      async_copy16(ldsB, gB + (size_t)(q << 3) * K + k0);
    }
    __syncthreads();
#pragma unroll
    for (int kk = 0; kk < 2; kk++) {
      bf16x8 af[4], bfr[4];
#pragma unroll
      for (int i = 0; i < 4; i++) {
        int row = wm + (i << 4) + (lane & 15);
        int slot = ((kk << 2) + (lane >> 4)) ^ (lane & 7);
        af[i] = *(const bf16x8*)&sA[(row << 6) + (slot << 3)];
      }
#pragma unroll
      for (int j = 0; j < 4; j++) {
        int row = wn + (j << 4) + (lane & 15);
        int slot = ((kk << 2) + (lane >> 4)) ^ (lane & 7);
        bfr[j] = *(const bf16x8*)&sB[(row << 6) + (slot << 3)];
      }
#pragma unroll
      for (int i = 0; i < 4; i++)
#pragma unroll
        for (int j = 0; j < 4; j++)
          acc[i][j] = __builtin_amdgcn_mfma_f32_16x16x32_bf16(af[i], bfr[j], acc[i][j], 0, 0, 0);
    }
    __syncthreads();
  }

  // ---- epilogue: LDS repack, coalesced stores (fully unrolled) ----
  unsigned short* sOut = sA;                 // 32 rows x stride 136
  const int cr = (lane >> 4) << 2;
  const int cc = lane & 15;
  const int lrb = ((wave >> 1) << 4) + cr;
  const int lr = tid >> 3, ch0 = tid & 7;
#pragma unroll
  for (int i = 0; i < 4; i++) {
    if (i) __syncthreads();
#pragma unroll
    for (int j = 0; j < 4; j++) {
      const int col = wn + (j << 4) + cc;
      const float bvv = bias[(bn << 7) + col];
#pragma unroll
      for (int r = 0; r < 4; r++) {
        float v = acc[i][j][r] + bvv;
        if constexpr (EPI == 2) {
          v = 0.5f * v * (1.0f + erff(v * 0.70710678118654752f));
        }
        sOut[(lrb + r) * 136 + col] = f2bf(v);
      }
    }
    __syncthreads();
    int grow = (bm << 7) + ((lr >> 4) << 6) + (i << 4) + (lr & 15);
#pragma unroll
    for (int cpart = 0; cpart < 2; cpart++) {
      int ch = ch0 + (cpart << 3);
      uint4 val = *(const uint4*)&sOut[lr * 136 + (ch << 3)];
      if constexpr (EPI == 3) {
        int gcol = (bn << 7) + (ch << 3);
        *(uint4*)&Cb[(size_t)(gcol >> 9) * qkvs + ((size_t)grow << 9) + (gcol & 511)] = val;
      } else {
        *(uint4*)&Cb[(size_t)grow * N + (bn << 7) + (ch << 3)] = val;
      }
    }
  }
}

// ---------------- embedding circular conv (C=7, W=3) -> bf16 ---------------
__global__ __launch_bounds__(256) void embed_kernel(const float* __restrict__ xe,
    const float* __restrict__ w, unsigned short* __restrict__ xb)
{
  int blk = blockIdx.x;             // nb * 64
  int b = blk >> 6, lg = blk & 63;
  int l0 = lg << 5;
  int tid = threadIdx.x;
  __shared__ float xwin[34 * 7];
  for (int i = tid; i < 34 * 7; i += 256) {
    int r = i / 7, c = i - r * 7;
    int sl = (l0 - 1 + r) & 2047;
    xwin[i] = xe[((size_t)(b * 2048 + sl)) * 7 + c];
  }
  __syncthreads();
  float wr0[21], wr1[21];
  const float* w0 = w + tid * 21;
  const float* w1 = w + (tid + 256) * 21;
#pragma unroll
  for (int k = 0; k < 21; k++) { wr0[k] = w0[k]; wr1[k] = w1[k]; }
#pragma unroll 1
  for (int ll = 0; ll < 32; ll++) {
    float a0 = 0.0f, a1 = 0.0f;
#pragma unroll
    for (int c = 0; c < 7; c++)
#pragma unroll
      for (int t = 0; t < 3; t++) {
        float xv = xwin[(ll + t) * 7 + c];
        a0 += xv * wr0[c * 3 + t];
        a1 += xv * wr1[c * 3 + t];
      }
    size_t o = ((size_t)(b * 2048 + l0 + ll)) << 9;
    xb[o + tid] = f2bf(a0);
    xb[o + 256 + tid] = f2bf(a1);
  }
}

// ---------------- M = max_j(qk_samp) - sum_j(qk_samp)/L --------------------
template<int U>
__global__ __launch_bounds__(256) void msamp_kernel(
    const unsigned short* __restrict__ qb, const unsigned short* __restrict__ kbuf,
    const int* __restrict__ idx, float* __restrict__ Mv, int L, int nlc, float invL,
    int xcdgrp)
{
  const int RB = 16;
  int blk = blockIdx.x;
  int b, lc;
  if (xcdgrp) {
    int xcd = blk & 7, slot = blk >> 3;
    int g = slot / nlc; lc = slot - g * nlc;
    b = g * 8 + xcd;
  } else {
    b = blk / nlc; lc = blk - b * nlc;
  }
  int l0 = lc * RB;
  int tid = threadIdx.x;
  int wave = tid >> 6, lane = tid & 63;
  int p = lane & 7, h = lane >> 3;
  __shared__ int iidx[RB * U];
  __shared__ float pM[RB * 8 * 25];

  for (int i = tid; i < RB * U; i += 256) iidx[i] = idx[l0 * U + i];
  __syncthreads();

  const size_t rowbase = ((size_t)(b * L)) << 9;
#pragma unroll
  for (int r = 0; r < RB / 4; r++) {
    int l = wave * (RB / 4) + r;
    uint4 qv = *(const uint4*)(qb + rowbase + (((size_t)(l0 + l)) << 9) + (lane << 3));
    float qf[8]; unpack8(qv, qf);
    int kr[U];
#pragma unroll
    for (int j = 0; j < U; j++) kr[j] = iidx[l * U + j];
#pragma unroll
    for (int j = 0; j < U; j++) {
      uint4 kv = *(const uint4*)(kbuf + rowbase + (((size_t)kr[j]) << 9) + (lane << 3));
      float s = dot8(kv, qf);
      s += __shfl_xor(s, 1);
      s += __shfl_xor(s, 2);
      s += __shfl_xor(s, 4);
      if (p == 0) pM[(l * 8 + h) * 25 + j] = s;
    }
  }
  __syncthreads();

  if (tid < RB * 8) {
    int l = tid >> 3, hh = tid & 7;
    float mx = -3.0e38f, sm = 0.0f;
    const float* pr = &pM[tid * 25];
    for (int j = 0; j < U; j++) { float v = pr[j]; mx = fmaxf(mx, v); sm += v; }
    Mv[((size_t)((b << 3) + hh)) * L + l0 + l] = mx - sm * invL;
  }
}

// ---------------- top-u: register-resident, shuffle-reduce -----------------
template<int S>
__global__ __launch_bounds__(256) void topk_kernel(const float* __restrict__ Mv,
    int* __restrict__ mtop, int L, int u)
{
  int bh = blockIdx.x; int tid = threadIdx.x;
  int wave = tid >> 6, lane = tid & 63;
  float lv[S];
#pragma unroll
  for (int s = 0; s < S; s++) lv[s] = Mv[(size_t)bh * L + s * 256 + tid];
  __shared__ float sv[4];
  __shared__ int si[4];
  for (int t = 0; t < u; t++) {
    float bv = lv[0]; int bs = 0;
#pragma unroll
    for (int s = 1; s < S; s++) if (lv[s] > bv) { bv = lv[s]; bs = s; }
    int bi = bs * 256 + tid;
#pragma unroll
    for (int o = 1; o < 64; o <<= 1) {
      float ov = __shfl_xor(bv, o); int oi = __shfl_xor(bi, o);
      if (ov > bv || (ov == bv && oi < bi)) { bv = ov; bi = oi; }
    }
    if (lane == 0) { sv[wave] = bv; si[wave] = bi; }
    __syncthreads();
    float wv = sv[0]; int wi = si[0];
#pragma unroll
    for (int w = 1; w < 4; w++) {
      float ov = sv[w]; int oi = si[w];
      if (ov > wv || (ov == wv && oi < wi)) { wv = ov; wi = oi; }
    }
    if (tid == 0) mtop[bh * u + t] = wi;
#pragma unroll
    for (int s = 0; s < S; s++)
      if (s == (wi >> 8) && (wi & 255) == tid) lv[s] = -3.0e38f;
    __syncthreads();
  }
}

// ---------------- attention part: one 256-row K/V chunk per block ----------
// LDS: pA and pB unioned (disjoint lifetimes) -> 32.9KB, 4 blocks/CU.
template<int U>
__device__ __forceinline__ void dot_rows(const unsigned short* __restrict__ krow,
                                         const float* __restrict__ qred, float* s)
{
#pragma unroll
  for (int j = 0; j < U; j++) s[j] = 0.0f;
  const uint4* kv4 = (const uint4*)krow;
#pragma unroll
  for (int d8 = 0; d8 < 8; d8++) {
    uint4 kv = kv4[d8];
    float kf[8];
    kf[0] = bf2f((unsigned short)(kv.x & 0xffff)); kf[1] = bf2f((unsigned short)(kv.x >> 16));
    kf[2] = bf2f((unsigned short)(kv.y & 0xffff)); kf[3] = bf2f((unsigned short)(kv.y >> 16));
    kf[4] = bf2f((unsigned short)(kv.z & 0xffff)); kf[5] = bf2f((unsigned short)(kv.z >> 16));
    kf[6] = bf2f((unsigned short)(kv.w & 0xffff)); kf[7] = bf2f((unsigned short)(kv.w >> 16));
#pragma unroll
    for (int j = 0; j < U; j++) {
      const float4 q0 = *(const float4*)&qred[j * 64 + d8 * 8];
      const float4 q1 = *(const float4*)&qred[j * 64 + d8 * 8 + 4];
      s[j] += kf[0] * q0.x + kf[1] * q0.y + kf[2] * q0.z + kf[3] * q0.w
            + kf[4] * q1.x + kf[5] * q1.y + kf[6] * q1.z + kf[7] * q1.w;
    }
  }
}

template<int U>
__global__ __launch_bounds__(256) void attn_part(
    const unsigned short* __restrict__ qb, const unsigned short* __restrict__ kbuf,
    const unsigned short* __restrict__ vbuf, const int* __restrict__ mtop,
    float* __restrict__ pupd, float* __restrict__ pden, float* __restrict__ pvs,
    int L, int S)
{
  int blk = blockIdx.x;
  int bh = blk / S, split = blk - bh * S;
  int b = bh >> 3, h = bh & 7;
  int tid = threadIdx.x;
  __shared__ float qred[U * 64];
  __shared__ float arena[U * 4 * 66];   // pA during exp+V pass; pB after
  __shared__ float pC[256];
  __shared__ float dnred[4 * U];
  float* pA = arena;
  float* pB = arena;                    // alias: pA dead before pB born

  for (int i = tid; i < U * 64; i += 256) {
    int j = i >> 6, d = i & 63;
    int row = mtop[bh * U + j];
    qred[i] = bf2f(qb[(((size_t)(b * L + row)) << 9) + h * 64 + d]) * 0.125f;
  }
  __syncthreads();

  int l = (split << 8) + tid;
  {
    float s[U];
    dot_rows<U>(kbuf + (((size_t)(b * L + l)) << 9) + h * 64, qred, s);
    int g0 = tid >> 6, d0 = tid & 63;
#pragma unroll
    for (int j = 0; j < U; j++) pA[(j * 4 + g0) * 66 + d0] = expf(s[j]);
  }
  __syncthreads();

  int g = tid >> 6, d = tid & 63;
  const unsigned short* vcol = vbuf + (((size_t)(b * L)) << 9) + h * 64 + d;
  float lupd[U], ldn[U]; float lvs = 0.0f;
#pragma unroll
  for (int j = 0; j < U; j++) { lupd[j] = 0.0f; ldn[j] = 0.0f; }
#pragma unroll 1
  for (int li = 0; li < 64; li++) {
    int ll = (split << 8) + (g << 6) + li;
    float vd = bf2f(vcol[(size_t)ll << 9]);
    lvs += vd;
#pragma unroll
    for (int j = 0; j < U; j++) {
      float pv = pA[(j * 4 + g) * 66 + li];
      ldn[j] += pv; lupd[j] += pv * vd;
    }
  }
  if (d == 0) {
#pragma unroll
    for (int j = 0; j < U; j++) dnred[g * U + j] = ldn[j];
  }
  pC[tid] = lvs;
  __syncthreads();              // all waves done reading pA
#pragma unroll
  for (int j = 0; j < U; j++) pB[(g * U + j) * 64 + d] = lupd[j];
  __syncthreads();

  size_t base = (size_t)bh * S + split;
  for (int i = tid; i < U * 64; i += 256) {
    int j = i >> 6, dd = i & 63;
    pupd[base * (U * 64) + i] = pB[j * 64 + dd] + pB[(U + j) * 64 + dd]
                              + pB[(2 * U + j) * 64 + dd] + pB[(3 * U + j) * 64 + dd];
  }
  if (tid < U)
    pden[base * U + tid] = dnred[tid] + dnred[U + tid] + dnred[2 * U + tid] + dnred[3 * U + tid];
  if (tid < 64)
    pvs[base * 64 + tid] = pC[tid] + pC[64 + tid] + pC[128 + tid] + pC[192 + tid];
}

// ---------------- attention combine: vmean bcast + top-row scatter ---------
template<int U>
__global__ __launch_bounds__(256) void attn_comb(
    const int* __restrict__ mtop, const float* __restrict__ pupd,
    const float* __restrict__ pden, const float* __restrict__ pvs,
    unsigned short* __restrict__ ab, int L, int S)
{
  int bh = blockIdx.x; int b = bh >> 3, h = bh & 7;
  int tid = threadIdx.x;
  __shared__ float updf[U * 64];
  __shared__ float den[U];
  __shared__ float vm[64];
  for (int i = tid; i < U * 64; i += 256) {
    float s = 0.0f;
    for (int sp = 0; sp < S; sp++) s += pupd[((size_t)bh * S + sp) * (U * 64) + i];
    updf[i] = s;
  }
  if (tid < U) {
    float s = 0.0f;
    for (int sp = 0; sp < S; sp++) s += pden[((size_t)bh * S + sp) * U + tid];
    den[tid] = s;
  }
  if (tid < 64) {
    float s = 0.0f;
    for (int sp = 0; sp < S; sp++) s += pvs[((size_t)bh * S + sp) * 64 + tid];
    vm[tid] = s / (float)L;
  }
  __syncthreads();
  int g = tid >> 6, d = tid & 63;
  unsigned short vmb = f2bf(vm[d]);
  for (int l = g; l < L; l += 4)
    ab[(((size_t)(b * L + l)) << 9) + h * 64 + d] = vmb;
  __syncthreads();
  for (int i = tid; i < U * 64; i += 256) {
    int j = i >> 6, dd = i & 63;
    int row = mtop[bh * U + j];
    ab[(((size_t)(b * L + row)) << 9) + h * 64 + dd] = f2bf(updf[i] / den[j]);
  }
}

// ---------------- layernorm, 512 cols; vectorized (2 elems/thread) ---------
__global__ __launch_bounds__(256) void ln_kernel(const unsigned short* __restrict__ xinb,
    const unsigned short* __restrict__ residb, const float* __restrict__ g,
    const float* __restrict__ beta, unsigned short* __restrict__ xbout,
    float* __restrict__ xfout)
{
  size_t base = (size_t)blockIdx.x * 512; int tid = threadIdx.x;
  int e = tid << 1;
  float v0 = 0.0f, v1 = 0.0f;
  if (xinb) {
    unsigned int x = *(const unsigned int*)&xinb[base + e];
    v0 += bf2f((unsigned short)(x & 0xffff)); v1 += bf2f((unsigned short)(x >> 16));
  }
  if (residb) {
    unsigned int x = *(const unsigned int*)&residb[base + e];
    v0 += bf2f((unsigned short)(x & 0xffff)); v1 += bf2f((unsigned short)(x >> 16));
  }
  __shared__ float red[256];
  __shared__ float smean, srstd;
  red[tid] = v0 + v1; __syncthreads();
  for (int s = 128; s > 0; s >>= 1) { if (tid < s) red[tid] += red[tid + s]; __syncthreads(); }
  if (tid == 0) smean = red[0] * (1.0f / 512.0f);
  __syncthreads();
  float m = smean;
  float d0 = v0 - m, d1 = v1 - m;
  red[tid] = d0 * d0 + d1 * d1; __syncthreads();
  for (int s = 128; s > 0; s >>= 1) { if (tid < s) red[tid] += red[tid + s]; __syncthreads(); }
  if (tid == 0) srstd = rsqrtf(red[0] * (1.0f / 512.0f) + 1e-5f);
  __syncthreads();
  float rs = srstd;
  float2 gv = *(const float2*)&g[e];
  float2 bv = *(const float2*)&beta[e];
  float o0 = d0 * rs * gv.x + bv.x;
  float o1 = d1 * rs * gv.y + bv.y;
  if (xbout) {
    unsigned int o = (unsigned int)f2bf(o0) | ((unsigned int)f2bf(o1) << 16);
    *(unsigned int*)&xbout[base + e] = o;
  }
  if (xfout) { *(float2*)&xfout[base + e] = make_float2(o0, o1); }
}

// ---------------- distil pool: vectorized (2 channels/thread) --------------
__global__ void pool_kernel(const unsigned short* __restrict__ z, const float* __restrict__ g,
    const float* __restrict__ beta, unsigned short* __restrict__ xbout, int L, int count)
{
  int i = blockIdx.x * 256 + threadIdx.x;   // over nb*(L/2)*256
  if (i >= count) return;
  int o2 = (i & 255) << 1; int r1 = i >> 8;
  int Lh = L >> 1;
  int l2 = r1 % Lh; int b = r1 / Lh;
  const float invs = 0.99999500003749969f;
  float g0 = g[o2] * invs, g1 = g[o2 + 1] * invs;
  float b0 = beta[o2], b1 = beta[o2 + 1];
  float m0 = -3.0e38f, m1 = -3.0e38f;
#pragma unroll
  for (int w = -1; w <= 1; w++) {
    int l = 2 * l2 + w;
    if (l >= 0 && l < L) {
      unsigned int x = *(const unsigned int*)&z[(size_t)(b * L + l) * DM + o2];
      float y0 = bf2f((unsigned short)(x & 0xffff)) * g0 + b0;
      float y1 = bf2f((unsigned short)(x >> 16)) * g1 + b1;
      y0 = (y0 > 0.0f) ? y0 : expm1f(y0);
      y1 = (y1 > 0.0f) ? y1 : expm1f(y1);
      m0 = fmaxf(m0, y0); m1 = fmaxf(m1, y1);
    }
  }
  unsigned int o = (unsigned int)f2bf(m0) | ((unsigned int)f2bf(m1) << 16);
  *(unsigned int*)&xbout[(size_t)(b * Lh + l2) * DM + o2] = o;
}

// ---------------- misc ------------------------------------------------------
__global__ void cvt_kernel(const float* __restrict__ in, unsigned short* __restrict__ out, int n) {
  int i = blockIdx.x * 256 + threadIdx.x;
  if (i < n) out[i] = f2bf(in[i]);
}

__global__ void cvt_qkv(const float* __restrict__ src, unsigned short* __restrict__ dst, int matoff) {
  int i = blockIdx.x * 256 + threadIdx.x;
  if (i >= 786432) return;
  int layer = i >> 18; int rem = i & 262143;
  dst[(size_t)layer * 786432 + matoff + rem] = f2bf(src[i]);
}

__global__ void catbias(const float* __restrict__ bq, const float* __restrict__ bk,
                        const float* __restrict__ bv, float* __restrict__ dst) {
  int i = blockIdx.x * 256 + threadIdx.x;
  if (i >= 3 * 1536) return;
  int layer = i / 1536, c = i - layer * 1536;
  float v = (c < 512) ? bq[layer * 512 + c]
          : (c < 1024) ? bk[layer * 512 + c - 512]
          : bv[layer * 512 + c - 1024];
  dst[i] = v;
}

__global__ void repack_dcw(const float* __restrict__ dcw, unsigned short* __restrict__ wt, int n) {
  int i = blockIdx.x * 256 + threadIdx.x;
  if (i >= n) return;
  int t = i % 3; int rest = i / 3; int c = rest % 512; int lo = rest / 512;
  wt[(size_t)lo * 1536 + t * 512 + c] = f2bf(dcw[i]);
}

// ---- 2-stage deterministic mean over L=512 rows (f32 input) ----
__global__ void mean_part(const float* __restrict__ xin, float* __restrict__ part, int nblkPerB) {
  int blk = blockIdx.x;
  int b = blk / nblkPerB, pc = blk - b * nblkPerB;
  int tid = threadIdx.x;
  float s0 = 0.0f, s1 = 0.0f;
  int l0 = pc * 32;
  for (int r = 0; r < 32; r++) {
    size_t base = ((size_t)(b * 512 + l0 + r)) << 9;
    s0 += xin[base + tid];
    s1 += xin[base + 256 + tid];
  }
  part[((size_t)blk << 9) + tid] = s0;
  part[((size_t)blk << 9) + 256 + tid] = s1;
}
__global__ void mean_fin(const float* __restrict__ part, float* __restrict__ out,
                         int nblkPerB, int nb) {
  int i = blockIdx.x * 256 + threadIdx.x;
  if (i >= nb * 512) return;
  int b = i >> 9, d = i & 511;
  float s = 0.0f;
  for (int c = 0; c < nblkPerB; c++) s += part[((size_t)(b * nblkPerB + c) << 9) + d];
  out[i] = s * (1.0f / 512.0f);
}

// ---------------- host ------------------------------------------------------
extern "C" void kernel_launch(void* const* d_in, const int* in_sizes, int n_in,
                              void* d_out, int out_size, void* d_ws, size_t ws_size,
                              hipStream_t stream)
{
  (void)in_sizes; (void)n_in; (void)out_size;
  const float* x_enc = (const float*)d_in[0];
  const float* emb_w = (const float*)d_in[1];
  const float* wq   = (const float*)d_in[2];
  const float* bq   = (const float*)d_in[3];
  const float* wk   = (const float*)d_in[4];
  const float* bk   = (const float*)d_in[5];
  const float* wv   = (const float*)d_in[6];
  const float* bvv  = (const float*)d_in[7];
  const float* wo   = (const float*)d_in[8];
  const float* bo   = (const float*)d_in[9];
  const float* c1w  = (const float*)d_in[10];
  const float* c1b  = (const float*)d_in[11];
  const float* c2w  = (const float*)d_in[12];
  const float* c2b  = (const float*)d_in[13];
  const float* ln1g = (const float*)d_in[14];
  const float* ln1b = (const float*)d_in[15];
  const float* ln2g = (const float*)d_in[16];
  const float* ln2b = (const float*)d_in[17];
  const float* dcw  = (const float*)d_in[18];
  const float* dcb  = (const float*)d_in[19];
  const float* bng  = (const float*)d_in[20];
  const float* bnb  = (const float*)d_in[21];
  const float* lnfg = (const float*)d_in[22];
  const float* lnfb = (const float*)d_in[23];

  // ---- choose batch-chunk size: need = 16MB + nb*8.8MB ----
  int nb = 32;
  while (nb > 1 && (16777216ull + (size_t)nb * 8804352ull) > ws_size) nb >>= 1;

  // ---- fixed small region (first 16MB) ----
  char* ws = (char*)d_ws;
  size_t off = 0;
  unsigned short* WQKV = (unsigned short*)(ws + off); off += 4718592ull;
  unsigned short* WOB  = (unsigned short*)(ws + off); off += 1572864ull;
  unsigned short* C1WB = (unsigned short*)(ws + off); off += 1572864ull;
  unsigned short* C2WB = (unsigned short*)(ws + off); off += 1572864ull;
  unsigned short* WTB  = (unsigned short*)(ws + off); off += 3145728ull;
  float* BQKVB         = (float*)(ws + off);          off += 18432ull;
  float* MP            = (float*)(ws + off);          off += 2097152ull;
  int* IDXP            = (int*)(ws + off);            off += 589824ull;
  int* MTOPP           = (int*)(ws + off);            off += 24576ull;

  // ---- chunk region ----
  size_t cb = 16777216ull;
  unsigned short* Xbf  = (unsigned short*)(ws + cb);
  char* R              = ws + cb + (size_t)nb * 2097152ull;
  unsigned short* DQ   = (unsigned short*)R;
  unsigned short* DK   = (unsigned short*)(R + (size_t)nb * 2097152ull);
  unsigned short* DV   = (unsigned short*)(R + (size_t)nb * 4194304ull);
  unsigned short* TMPB = DQ;                             // bf16 GEMM out (Q dead)
  float* TMPF          = (float*)DK;                     // final-LN f32 (K dead)
  unsigned short* AB   = DV;                             // ctx/ffn-mid (V dead)
  float* PUPD          = (float*)(ws + cb + (size_t)nb * 8388608ull);
  float* PDEN          = (float*)((char*)PUPD + (size_t)nb * 393216ull);
  float* PVS           = (float*)((char*)PDEN + (size_t)nb * 6144ull);
  const size_t qkvs    = (size_t)nb * 1048576ull;

  // ---- weights to bf16 (once) ----
  {
    int nw = 3 * 512 * 512;
    int blocks = (nw + 255) / 256;
    cvt_qkv<<<blocks, 256, 0, stream>>>(wq, WQKV, 0);
    cvt_qkv<<<blocks, 256, 0, stream>>>(wk, WQKV, 262144);
    cvt_qkv<<<blocks, 256, 0, stream>>>(wv, WQKV, 524288);
    catbias<<<18, 256, 0, stream>>>(bq, bk, bvv, BQKVB);
    cvt_kernel<<<blocks, 256, 0, stream>>>(wo,  WOB,  nw);
    cvt_kernel<<<blocks, 256, 0, stream>>>(c1w, C1WB, nw);
    cvt_kernel<<<blocks, 256, 0, stream>>>(c2w, C2WB, nw);
    int nd = 2 * 512 * 512 * 3;
    repack_dcw<<<(nd + 255) / 256, 256, 0, stream>>>(dcw, WTB, nd);
  }

  // ---- sample indices per layer (once) ----
  for (int layer = 0; layer < 3; layer++) {
    int Ll = (layer == 0) ? 2048 : (layer == 1 ? 1024 : 512);
    int ul = (layer == 0) ? 24 : 21;
    uint32_t f0, f1, a0, b0k, a1, b1k;
    tf2x32(0u, 42u, 0u, (uint32_t)layer, &f0, &f1);
    tf2x32(f0, f1, 0u, 2u, &a0, &b0k);
    tf2x32(f0, f1, 1u, 3u, &a1, &b1k);
    (void)a0; (void)a1;
    int nhalf = Ll * ul / 2;
    idx_kernel<<<(nhalf + 255) / 256, 256, 0, stream>>>(IDXP + layer * 49152, nhalf, b0k, b1k, Ll - 1);
  }

  // ---- per-chunk full pipeline ----
  for (int b0 = 0; b0 < 32; b0 += nb) {
    embed_kernel<<<nb * 64, 256, 0, stream>>>(x_enc + (size_t)b0 * 2048 * 7, emb_w, Xbf);

    int L = 2048, Lsh = 11;
    for (int layer = 0; layer < 3; layer++) {
      const int M_ = nb * L;
      const int u = (layer == 0) ? 24 : 21;
      const int S = L >> 8;
      const int nbm = M_ / 128;
      const int ng  = 4 * nbm;
      const int ngq = 12 * nbm;
      const int xsg  = (ng  % 8 == 0) ? 1 : 0;
      const int xsgq = (ngq % 8 == 0) ? 1 : 0;
      const int xg = (nb % 8 == 0) ? 1 : 0;

      gemm_bt<3,0><<<ngq, 256, 0, stream>>>(Xbf, WQKV + (size_t)layer * 786432, BQKVB + layer * 1536, DQ, M_, 1536, 512, 0, 0, qkvs, 12, xsgq);

      if (u == 24) msamp_kernel<24><<<nb * (L / 16), 256, 0, stream>>>(DQ, DK, IDXP + layer * 49152, MP, L, L / 16, 1.0f / (float)L, xg);
      else         msamp_kernel<21><<<nb * (L / 16), 256, 0, stream>>>(DQ, DK, IDXP + layer * 49152, MP, L, L / 16, 1.0f / (float)L, xg);

      if (L == 2048)      topk_kernel<8><<<nb * 8, 256, 0, stream>>>(MP, MTOPP, L, u);
      else if (L == 1024) topk_kernel<4><<<nb * 8, 256, 0, stream>>>(MP, MTOPP, L, u);
      else                topk_kernel<2><<<nb * 8, 256, 0, stream>>>(MP, MTOPP, L, u);

      if (u == 24) {
        attn_part<24><<<nb * 8 * S, 256, 0, stream>>>(DQ, DK, DV, MTOPP, PUPD, PDEN, PVS, L, S);
        attn_comb<24><<<nb * 8, 256, 0, stream>>>(MTOPP, PUPD, PDEN, PVS, AB, L, S);
      } else {
        attn_part<21><<<nb * 8 * S, 256, 0, stream>>>(DQ, DK, DV, MTOPP, PUPD, PDEN, PVS, L, S);
        attn_comb<21><<<nb * 8, 256, 0, stream>>>(MTOPP, PUPD, PDEN, PVS, AB, L, S);
      }

      // Q/K/V dead; TMPB (=DQ) live from here.
      gemm_bt<1,0><<<ng, 256, 0, stream>>>(AB, WOB + (size_t)layer * 262144, bo + layer * 512, TMPB, M_, 512, 512, 0, 0, 0, 4, xsg);
      ln_kernel<<<M_, 256, 0, stream>>>(TMPB, Xbf, ln1g + layer * 512, ln1b + layer * 512, Xbf, nullptr);
      gemm_bt<2,0><<<ng, 256, 0, stream>>>(Xbf, C1WB + (size_t)layer * 262144, c1b + layer * 512, AB, M_, 512, 512, 0, 0, 0, 4, xsg);
      gemm_bt<1,0><<<ng, 256, 0, stream>>>(AB, C2WB + (size_t)layer * 262144, c2b + layer * 512, TMPB, M_, 512, 512, 0, 0, 0, 4, xsg);
      ln_kernel<<<M_, 256, 0, stream>>>(TMPB, Xbf, ln2g + layer * 512, ln2b + layer * 512, Xbf, nullptr);

      if (layer < 2) {
        gemm_bt<1,1><<<ng, 256, 0, stream>>>(Xbf, WTB + (size_t)layer * 786432, dcb + layer * 512, TMPB, M_, 512, 1536, L, Lsh, 0, 4, xsg);
        pool_kernel<<<nb * (L / 2), 256, 0, stream>>>(TMPB, bng + layer * 512, bnb + layer * 512, Xbf, L, nb * (L / 2) * 256);
        L >>= 1; Lsh -= 1;
      }
    }

    ln_kernel<<<nb * 512, 256, 0, stream>>>(nullptr, Xbf, lnfg, lnfb, nullptr, TMPF);
    mean_part<<<nb * 16, 256, 0, stream>>>(TMPF, MP, 16);
    mean_fin<<<(nb * 512 + 255) / 256, 256, 0, stream>>>(MP, (float*)d_out + (size_t)b0 * 512, 16, nb);
  }
}

// Round 18
// 2115.233 us; speedup vs baseline: 3.4370x; 1.0161x over previous
//
#include <hip/hip_runtime.h>
#include <stdint.h>

#define DM 512
#define DH 64

typedef __bf16 bf16x8 __attribute__((ext_vector_type(8)));
typedef float f32x4 __attribute__((ext_vector_type(4)));

__device__ __forceinline__ float bf2f(unsigned short h) {
  union { unsigned int u; float f; } c; c.u = ((unsigned int)h) << 16; return c.f;
}
__device__ __forceinline__ unsigned short f2bf(float f) {
  union { float f; unsigned int u; } c; c.f = f;
  unsigned int u = c.u;
  return (unsigned short)((u + 0x7FFFu + ((u >> 16) & 1u)) >> 16);
}
__device__ __forceinline__ void unpack8(uint4 v, float* f) {
  f[0] = bf2f((unsigned short)(v.x & 0xffff)); f[1] = bf2f((unsigned short)(v.x >> 16));
  f[2] = bf2f((unsigned short)(v.y & 0xffff)); f[3] = bf2f((unsigned short)(v.y >> 16));
  f[4] = bf2f((unsigned short)(v.z & 0xffff)); f[5] = bf2f((unsigned short)(v.z >> 16));
  f[6] = bf2f((unsigned short)(v.w & 0xffff)); f[7] = bf2f((unsigned short)(v.w >> 16));
}
__device__ __forceinline__ float dot8(uint4 kv, const float* qf) {
  float s;
  s  = bf2f((unsigned short)(kv.x & 0xffff)) * qf[0];
  s += bf2f((unsigned short)(kv.x >> 16))    * qf[1];
  s += bf2f((unsigned short)(kv.y & 0xffff)) * qf[2];
  s += bf2f((unsigned short)(kv.y >> 16))    * qf[3];
  s += bf2f((unsigned short)(kv.z & 0xffff)) * qf[4];
  s += bf2f((unsigned short)(kv.z >> 16))    * qf[5];
  s += bf2f((unsigned short)(kv.w & 0xffff)) * qf[6];
  s += bf2f((unsigned short)(kv.w >> 16))    * qf[7];
  return s;
}

// ---------------- Threefry-2x32 (20 rounds), JAX-compatible ----------------
__host__ __device__ inline void tf2x32(uint32_t k0, uint32_t k1, uint32_t x0, uint32_t x1,
                                       uint32_t* o0, uint32_t* o1) {
  uint32_t ks2 = k0 ^ k1 ^ 0x1BD11BDAu;
#define TFR(r) { x0 += x1; x1 = (x1 << r) | (x1 >> (32 - r)); x1 ^= x0; }
  x0 += k0; x1 += k1;
  TFR(13) TFR(15) TFR(26) TFR(6)
  x0 += k1; x1 += ks2 + 1u;
  TFR(17) TFR(29) TFR(16) TFR(24)
  x0 += ks2; x1 += k0 + 2u;
  TFR(13) TFR(15) TFR(26) TFR(6)
  x0 += k0; x1 += k1 + 3u;
  TFR(17) TFR(29) TFR(16) TFR(24)
  x0 += k1; x1 += ks2 + 4u;
  TFR(13) TFR(15) TFR(26) TFR(6)
  *o0 = x0 + ks2; *o1 = x1 + k0 + 5u;
#undef TFR
}

__global__ void idx_kernel(int* __restrict__ idx, int nhalf, unsigned int k0, unsigned int k1, int mask) {
  int m = blockIdx.x * 256 + threadIdx.x;
  if (m >= nhalf) return;
  uint32_t o0, o1;
  tf2x32(k0, k1, (uint32_t)m, (uint32_t)(m + nhalf), &o0, &o1);
  idx[m] = (int)(o0 & (uint32_t)mask);
  idx[m + nhalf] = (int)(o1 & (uint32_t)mask);
}

// ---------------- bf16 GEMM: C(M,N) = A(M,K) * B(N,K)^T + bias -------------
// 1D grid, XCD-bijective swizzle; bn = wgid % NBN (fast), bm = wgid / NBN.
// BK=64 (8 K-iters at K=512); XOR-swizzled LDS via pre-swizzled global src.
// Epilogue: fully unrolled (rule #20); LDS-repacked coalesced 16B stores.
// EPI: 1 = bf16; 2 = gelu->bf16; 3 = bf16 QKV-split (col>>9 selects Q/K/V).
// CIRC: logical A row m, col k -> A[b*L + ((l-1+t) mod L)][k%512], t=k/512.
__device__ __forceinline__ void async_copy16(void* lds, const void* g) {
  __builtin_amdgcn_global_load_lds((const __attribute__((address_space(1))) unsigned int*)g,
                                   (__attribute__((address_space(3))) unsigned int*)lds,
                                   16, 0, 0);
}

template<int EPI, int CIRC>
__global__ __launch_bounds__(256) void gemm_bt(
    const unsigned short* __restrict__ A, const unsigned short* __restrict__ Bw,
    const float* __restrict__ bias, unsigned short* __restrict__ Cb,
    int M, int N, int K, int L, int Lsh, size_t qkvs, int NBN, int xswz)
{
  __shared__ unsigned short sA[128 * 64];
  __shared__ unsigned short sB[128 * 64];
  const int tid = threadIdx.x;
  const int wave = tid >> 6, lane = tid & 63;

  int blk = blockIdx.x;
  if (xswz) { int cpx = (int)gridDim.x >> 3; blk = (blk & 7) * cpx + (blk >> 3); }
  const int bn = blk % NBN, bm = blk / NBN;

  const int wm = (wave >> 1) << 6, wn = (wave & 1) << 6;

  const int srow = (wave << 5) + (lane >> 3);
  const int kb = (((lane & 7) ^ ((lane >> 3) & 7)) << 3);

  const unsigned short* gA = nullptr;
  int lI = 0;
  if constexpr (CIRC) {
    int r = bm * 128 + srow;
    lI = r & (L - 1);
  } else {
    gA = A + (size_t)(bm * 128 + srow) * K + kb;
  }
  const unsigned short* gB = Bw + (size_t)(bn * 128 + srow) * K + kb;

  f32x4 acc[4][4] = {};

  for (int k0 = 0; k0 < K; k0 += 64) {
#pragma unroll
    for (int q = 0; q < 4; q++) {
      unsigned short* ldsA = &sA[((wave << 5) + (q << 3)) << 6];
      unsigned short* ldsB = &sB[((wave << 5) + (q << 3)) << 6];
      if constexpr (CIRC) {
        int t = k0 >> 9;
        int kk = (k0 & 511) + kb;
        int sl = (lI + (q << 3) - 1 + t + L) & (L - 1);
        int bq = (bm * 128 + srow + (q << 3)) >> Lsh;
        async_copy16(ldsA, A + (((size_t)(bq * L + sl)) << 9) + kk);
      } else {
        async_copy16(ldsA, gA + (size_t)(q << 3) * K + k0);
      }
      async_copy16(ldsB, gB + (size_t)(q << 3) * K + k0);
    }
    __syncthreads();
#pragma unroll
    for (int kk = 0; kk < 2; kk++) {
      bf16x8 af[4], bfr[4];
#pragma unroll
      for (int i = 0; i < 4; i++) {
        int row = wm + (i << 4) + (lane & 15);
        int slot = ((kk << 2) + (lane >> 4)) ^ (lane & 7);
        af[i] = *(const bf16x8*)&sA[(row << 6) + (slot << 3)];
      }
#pragma unroll
      for (int j = 0; j < 4; j++) {
        int row = wn + (j << 4) + (lane & 15);
        int slot = ((kk << 2) + (lane >> 4)) ^ (lane & 7);
        bfr[j] = *(const bf16x8*)&sB[(row << 6) + (slot << 3)];
      }
#pragma unroll
      for (int i = 0; i < 4; i++)
#pragma unroll
        for (int j = 0; j < 4; j++)
          acc[i][j] = __builtin_amdgcn_mfma_f32_16x16x32_bf16(af[i], bfr[j], acc[i][j], 0, 0, 0);
    }
    __syncthreads();
  }

  // ---- epilogue: LDS repack, coalesced stores (fully unrolled) ----
  unsigned short* sOut = sA;                 // 32 rows x stride 136
  const int cr = (lane >> 4) << 2;
  const int cc = lane & 15;
  const int lrb = ((wave >> 1) << 4) + cr;
  const int lr = tid >> 3, ch0 = tid & 7;
#pragma unroll
  for (int i = 0; i < 4; i++) {
    if (i) __syncthreads();
#pragma unroll
    for (int j = 0; j < 4; j++) {
      const int col = wn + (j << 4) + cc;
      const float bvv = bias[(bn << 7) + col];
#pragma unroll
      for (int r = 0; r < 4; r++) {
        float v = acc[i][j][r] + bvv;
        if constexpr (EPI == 2) {
          v = 0.5f * v * (1.0f + erff(v * 0.70710678118654752f));
        }
        sOut[(lrb + r) * 136 + col] = f2bf(v);
      }
    }
    __syncthreads();
    int grow = (bm << 7) + ((lr >> 4) << 6) + (i << 4) + (lr & 15);
#pragma unroll
    for (int cpart = 0; cpart < 2; cpart++) {
      int ch = ch0 + (cpart << 3);
      uint4 val = *(const uint4*)&sOut[lr * 136 + (ch << 3)];
      if constexpr (EPI == 3) {
        int gcol = (bn << 7) + (ch << 3);
        *(uint4*)&Cb[(size_t)(gcol >> 9) * qkvs + ((size_t)grow << 9) + (gcol & 511)] = val;
      } else {
        *(uint4*)&Cb[(size_t)grow * N + (bn << 7) + (ch << 3)] = val;
      }
    }
  }
}

// ---------------- embedding circular conv (C=7, W=3) -> bf16 ---------------
__global__ __launch_bounds__(256) void embed_kernel(const float* __restrict__ xe,
    const float* __restrict__ w, unsigned short* __restrict__ xb)
{
  int blk = blockIdx.x;             // nb * 64
  int b = blk >> 6, lg = blk & 63;
  int l0 = lg << 5;
  int tid = threadIdx.x;
  __shared__ float xwin[34 * 7];
  for (int i = tid; i < 34 * 7; i += 256) {
    int r = i / 7, c = i - r * 7;
    int sl = (l0 - 1 + r) & 2047;
    xwin[i] = xe[((size_t)(b * 2048 + sl)) * 7 + c];
  }
  __syncthreads();
  float wr0[21], wr1[21];
  const float* w0 = w + tid * 21;
  const float* w1 = w + (tid + 256) * 21;
#pragma unroll
  for (int k = 0; k < 21; k++) { wr0[k] = w0[k]; wr1[k] = w1[k]; }
#pragma unroll 1
  for (int ll = 0; ll < 32; ll++) {
    float a0 = 0.0f, a1 = 0.0f;
#pragma unroll
    for (int c = 0; c < 7; c++)
#pragma unroll
      for (int t = 0; t < 3; t++) {
        float xv = xwin[(ll + t) * 7 + c];
        a0 += xv * wr0[c * 3 + t];
        a1 += xv * wr1[c * 3 + t];
      }
    size_t o = ((size_t)(b * 2048 + l0 + ll)) << 9;
    xb[o + tid] = f2bf(a0);
    xb[o + 256 + tid] = f2bf(a1);
  }
}

// ---------------- M = max_j(qk_samp) - sum_j(qk_samp)/L --------------------
template<int U>
__global__ __launch_bounds__(256) void msamp_kernel(
    const unsigned short* __restrict__ qb, const unsigned short* __restrict__ kbuf,
    const int* __restrict__ idx, float* __restrict__ Mv, int L, int nlc, float invL,
    int xcdgrp)
{
  const int RB = 16;
  int blk = blockIdx.x;
  int b, lc;
  if (xcdgrp) {
    int xcd = blk & 7, slot = blk >> 3;
    int g = slot / nlc; lc = slot - g * nlc;
    b = g * 8 + xcd;
  } else {
    b = blk / nlc; lc = blk - b * nlc;
  }
  int l0 = lc * RB;
  int tid = threadIdx.x;
  int wave = tid >> 6, lane = tid & 63;
  int p = lane & 7, h = lane >> 3;
  __shared__ int iidx[RB * U];
  __shared__ float pM[RB * 8 * 25];

  for (int i = tid; i < RB * U; i += 256) iidx[i] = idx[l0 * U + i];
  __syncthreads();

  const size_t rowbase = ((size_t)(b * L)) << 9;
#pragma unroll
  for (int r = 0; r < RB / 4; r++) {
    int l = wave * (RB / 4) + r;
    uint4 qv = *(const uint4*)(qb + rowbase + (((size_t)(l0 + l)) << 9) + (lane << 3));
    float qf[8]; unpack8(qv, qf);
    int kr[U];
#pragma unroll
    for (int j = 0; j < U; j++) kr[j] = iidx[l * U + j];
#pragma unroll
    for (int j = 0; j < U; j++) {
      uint4 kv = *(const uint4*)(kbuf + rowbase + (((size_t)kr[j]) << 9) + (lane << 3));
      float s = dot8(kv, qf);
      s += __shfl_xor(s, 1);
      s += __shfl_xor(s, 2);
      s += __shfl_xor(s, 4);
      if (p == 0) pM[(l * 8 + h) * 25 + j] = s;
    }
  }
  __syncthreads();

  if (tid < RB * 8) {
    int l = tid >> 3, hh = tid & 7;
    float mx = -3.0e38f, sm = 0.0f;
    const float* pr = &pM[tid * 25];
    for (int j = 0; j < U; j++) { float v = pr[j]; mx = fmaxf(mx, v); sm += v; }
    Mv[((size_t)((b << 3) + hh)) * L + l0 + l] = mx - sm * invL;
  }
}

// ---------------- top-u: register-resident, shuffle-reduce -----------------
template<int S>
__global__ __launch_bounds__(256) void topk_kernel(const float* __restrict__ Mv,
    int* __restrict__ mtop, int L, int u)
{
  int bh = blockIdx.x; int tid = threadIdx.x;
  int wave = tid >> 6, lane = tid & 63;
  float lv[S];
#pragma unroll
  for (int s = 0; s < S; s++) lv[s] = Mv[(size_t)bh * L + s * 256 + tid];
  __shared__ float sv[4];
  __shared__ int si[4];
  for (int t = 0; t < u; t++) {
    float bv = lv[0]; int bs = 0;
#pragma unroll
    for (int s = 1; s < S; s++) if (lv[s] > bv) { bv = lv[s]; bs = s; }
    int bi = bs * 256 + tid;
#pragma unroll
    for (int o = 1; o < 64; o <<= 1) {
      float ov = __shfl_xor(bv, o); int oi = __shfl_xor(bi, o);
      if (ov > bv || (ov == bv && oi < bi)) { bv = ov; bi = oi; }
    }
    if (lane == 0) { sv[wave] = bv; si[wave] = bi; }
    __syncthreads();
    float wv = sv[0]; int wi = si[0];
#pragma unroll
    for (int w = 1; w < 4; w++) {
      float ov = sv[w]; int oi = si[w];
      if (ov > wv || (ov == wv && oi < wi)) { wv = ov; wi = oi; }
    }
    if (tid == 0) mtop[bh * u + t] = wi;
#pragma unroll
    for (int s = 0; s < S; s++)
      if (s == (wi >> 8) && (wi & 255) == tid) lv[s] = -3.0e38f;
    __syncthreads();
  }
}

// ---------------- attention part: one 256-row K/V chunk per block ----------
// LDS: pA and pB unioned (disjoint lifetimes) -> 32.9KB, 4 blocks/CU.
// V-loop unrolled x4 (batched vd loads) for global-latency ILP; summation
// order unchanged (q ascending == li ascending) -> bit-identical.
template<int U>
__device__ __forceinline__ void dot_rows(const unsigned short* __restrict__ krow,
                                         const float* __restrict__ qred, float* s)
{
#pragma unroll
  for (int j = 0; j < U; j++) s[j] = 0.0f;
  const uint4* kv4 = (const uint4*)krow;
#pragma unroll
  for (int d8 = 0; d8 < 8; d8++) {
    uint4 kv = kv4[d8];
    float kf[8];
    kf[0] = bf2f((unsigned short)(kv.x & 0xffff)); kf[1] = bf2f((unsigned short)(kv.x >> 16));
    kf[2] = bf2f((unsigned short)(kv.y & 0xffff)); kf[3] = bf2f((unsigned short)(kv.y >> 16));
    kf[4] = bf2f((unsigned short)(kv.z & 0xffff)); kf[5] = bf2f((unsigned short)(kv.z >> 16));
    kf[6] = bf2f((unsigned short)(kv.w & 0xffff)); kf[7] = bf2f((unsigned short)(kv.w >> 16));
#pragma unroll
    for (int j = 0; j < U; j++) {
      const float4 q0 = *(const float4*)&qred[j * 64 + d8 * 8];
      const float4 q1 = *(const float4*)&qred[j * 64 + d8 * 8 + 4];
      s[j] += kf[0] * q0.x + kf[1] * q0.y + kf[2] * q0.z + kf[3] * q0.w
            + kf[4] * q1.x + kf[5] * q1.y + kf[6] * q1.z + kf[7] * q1.w;
    }
  }
}

template<int U>
__global__ __launch_bounds__(256) void attn_part(
    const unsigned short* __restrict__ qb, const unsigned short* __restrict__ kbuf,
    const unsigned short* __restrict__ vbuf, const int* __restrict__ mtop,
    float* __restrict__ pupd, float* __restrict__ pden, float* __restrict__ pvs,
    int L, int S)
{
  int blk = blockIdx.x;
  int bh = blk / S, split = blk - bh * S;
  int b = bh >> 3, h = bh & 7;
  int tid = threadIdx.x;
  __shared__ float qred[U * 64];
  __shared__ float arena[U * 4 * 66];   // pA during exp+V pass; pB after
  __shared__ float pC[256];
  __shared__ float dnred[4 * U];
  float* pA = arena;
  float* pB = arena;                    // alias: pA dead before pB born

  for (int i = tid; i < U * 64; i += 256) {
    int j = i >> 6, d = i & 63;
    int row = mtop[bh * U + j];
    qred[i] = bf2f(qb[(((size_t)(b * L + row)) << 9) + h * 64 + d]) * 0.125f;
  }
  __syncthreads();

  int l = (split << 8) + tid;
  {
    float s[U];
    dot_rows<U>(kbuf + (((size_t)(b * L + l)) << 9) + h * 64, qred, s);
    int g0 = tid >> 6, d0 = tid & 63;
#pragma unroll
    for (int j = 0; j < U; j++) pA[(j * 4 + g0) * 66 + d0] = expf(s[j]);
  }
  __syncthreads();

  int g = tid >> 6, d = tid & 63;
  const unsigned short* vcol = vbuf + (((size_t)(b * L)) << 9) + h * 64 + d;
  float lupd[U], ldn[U]; float lvs = 0.0f;
#pragma unroll
  for (int j = 0; j < U; j++) { lupd[j] = 0.0f; ldn[j] = 0.0f; }
#pragma unroll 1
  for (int li = 0; li < 64; li += 4) {
    float vd[4];
#pragma unroll
    for (int q = 0; q < 4; q++) {
      int ll = (split << 8) + (g << 6) + li + q;
      vd[q] = bf2f(vcol[(size_t)ll << 9]);
    }
#pragma unroll
    for (int q = 0; q < 4; q++) {
      lvs += vd[q];
#pragma unroll
      for (int j = 0; j < U; j++) {
        float pv = pA[(j * 4 + g) * 66 + li + q];
        ldn[j] += pv; lupd[j] += pv * vd[q];
      }
    }
  }
  if (d == 0) {
#pragma unroll
    for (int j = 0; j < U; j++) dnred[g * U + j] = ldn[j];
  }
  pC[tid] = lvs;
  __syncthreads();              // all waves done reading pA
#pragma unroll
  for (int j = 0; j < U; j++) pB[(g * U + j) * 64 + d] = lupd[j];
  __syncthreads();

  size_t base = (size_t)bh * S + split;
  for (int i = tid; i < U * 64; i += 256) {
    int j = i >> 6, dd = i & 63;
    pupd[base * (U * 64) + i] = pB[j * 64 + dd] + pB[(U + j) * 64 + dd]
                              + pB[(2 * U + j) * 64 + dd] + pB[(3 * U + j) * 64 + dd];
  }
  if (tid < U)
    pden[base * U + tid] = dnred[tid] + dnred[U + tid] + dnred[2 * U + tid] + dnred[3 * U + tid];
  if (tid < 64)
    pvs[base * 64 + tid] = pC[tid] + pC[64 + tid] + pC[128 + tid] + pC[192 + tid];
}

// ---------------- attention combine: vmean bcast + top-row scatter ---------
template<int U>
__global__ __launch_bounds__(256) void attn_comb(
    const int* __restrict__ mtop, const float* __restrict__ pupd,
    const float* __restrict__ pden, const float* __restrict__ pvs,
    unsigned short* __restrict__ ab, int L, int S)
{
  int bh = blockIdx.x; int b = bh >> 3, h = bh & 7;
  int tid = threadIdx.x;
  __shared__ float updf[U * 64];
  __shared__ float den[U];
  __shared__ float vm[64];
  for (int i = tid; i < U * 64; i += 256) {
    float s = 0.0f;
    for (int sp = 0; sp < S; sp++) s += pupd[((size_t)bh * S + sp) * (U * 64) + i];
    updf[i] = s;
  }
  if (tid < U) {
    float s = 0.0f;
    for (int sp = 0; sp < S; sp++) s += pden[((size_t)bh * S + sp) * U + tid];
    den[tid] = s;
  }
  if (tid < 64) {
    float s = 0.0f;
    for (int sp = 0; sp < S; sp++) s += pvs[((size_t)bh * S + sp) * 64 + tid];
    vm[tid] = s / (float)L;
  }
  __syncthreads();
  int g = tid >> 6, d = tid & 63;
  unsigned short vmb = f2bf(vm[d]);
  for (int l = g; l < L; l += 4)
    ab[(((size_t)(b * L + l)) << 9) + h * 64 + d] = vmb;
  __syncthreads();
  for (int i = tid; i < U * 64; i += 256) {
    int j = i >> 6, dd = i & 63;
    int row = mtop[bh * U + j];
    ab[(((size_t)(b * L + row)) << 9) + h * 64 + dd] = f2bf(updf[i] / den[j]);
  }
}

// ---------------- layernorm, 512 cols; vectorized (2 elems/thread) ---------
__global__ __launch_bounds__(256) void ln_kernel(const unsigned short* __restrict__ xinb,
    const unsigned short* __restrict__ residb, const float* __restrict__ g,
    const float* __restrict__ beta, unsigned short* __restrict__ xbout,
    float* __restrict__ xfout)
{
  size_t base = (size_t)blockIdx.x * 512; int tid = threadIdx.x;
  int e = tid << 1;
  float v0 = 0.0f, v1 = 0.0f;
  if (xinb) {
    unsigned int x = *(const unsigned int*)&xinb[base + e];
    v0 += bf2f((unsigned short)(x & 0xffff)); v1 += bf2f((unsigned short)(x >> 16));
  }
  if (residb) {
    unsigned int x = *(const unsigned int*)&residb[base + e];
    v0 += bf2f((unsigned short)(x & 0xffff)); v1 += bf2f((unsigned short)(x >> 16));
  }
  __shared__ float red[256];
  __shared__ float smean, srstd;
  red[tid] = v0 + v1; __syncthreads();
  for (int s = 128; s > 0; s >>= 1) { if (tid < s) red[tid] += red[tid + s]; __syncthreads(); }
  if (tid == 0) smean = red[0] * (1.0f / 512.0f);
  __syncthreads();
  float m = smean;
  float d0 = v0 - m, d1 = v1 - m;
  red[tid] = d0 * d0 + d1 * d1; __syncthreads();
  for (int s = 128; s > 0; s >>= 1) { if (tid < s) red[tid] += red[tid + s]; __syncthreads(); }
  if (tid == 0) srstd = rsqrtf(red[0] * (1.0f / 512.0f) + 1e-5f);
  __syncthreads();
  float rs = srstd;
  float2 gv = *(const float2*)&g[e];
  float2 bv = *(const float2*)&beta[e];
  float o0 = d0 * rs * gv.x + bv.x;
  float o1 = d1 * rs * gv.y + bv.y;
  if (xbout) {
    unsigned int o = (unsigned int)f2bf(o0) | ((unsigned int)f2bf(o1) << 16);
    *(unsigned int*)&xbout[base + e] = o;
  }
  if (xfout) { *(float2*)&xfout[base + e] = make_float2(o0, o1); }
}

// ---------------- distil pool: vectorized (2 channels/thread) --------------
__global__ void pool_kernel(const unsigned short* __restrict__ z, const float* __restrict__ g,
    const float* __restrict__ beta, unsigned short* __restrict__ xbout, int L, int count)
{
  int i = blockIdx.x * 256 + threadIdx.x;   // over nb*(L/2)*256
  if (i >= count) return;
  int o2 = (i & 255) << 1; int r1 = i >> 8;
  int Lh = L >> 1;
  int l2 = r1 % Lh; int b = r1 / Lh;
  const float invs = 0.99999500003749969f;
  float g0 = g[o2] * invs, g1 = g[o2 + 1] * invs;
  float b0 = beta[o2], b1 = beta[o2 + 1];
  float m0 = -3.0e38f, m1 = -3.0e38f;
#pragma unroll
  for (int w = -1; w <= 1; w++) {
    int l = 2 * l2 + w;
    if (l >= 0 && l < L) {
      unsigned int x = *(const unsigned int*)&z[(size_t)(b * L + l) * DM + o2];
      float y0 = bf2f((unsigned short)(x & 0xffff)) * g0 + b0;
      float y1 = bf2f((unsigned short)(x >> 16)) * g1 + b1;
      y0 = (y0 > 0.0f) ? y0 : expm1f(y0);
      y1 = (y1 > 0.0f) ? y1 : expm1f(y1);
      m0 = fmaxf(m0, y0); m1 = fmaxf(m1, y1);
    }
  }
  unsigned int o = (unsigned int)f2bf(m0) | ((unsigned int)f2bf(m1) << 16);
  *(unsigned int*)&xbout[(size_t)(b * Lh + l2) * DM + o2] = o;
}

// ---------------- misc ------------------------------------------------------
__global__ void cvt_kernel(const float* __restrict__ in, unsigned short* __restrict__ out, int n) {
  int i = blockIdx.x * 256 + threadIdx.x;
  if (i < n) out[i] = f2bf(in[i]);
}

__global__ void cvt_qkv(const float* __restrict__ src, unsigned short* __restrict__ dst, int matoff) {
  int i = blockIdx.x * 256 + threadIdx.x;
  if (i >= 786432) return;
  int layer = i >> 18; int rem = i & 262143;
  dst[(size_t)layer * 786432 + matoff + rem] = f2bf(src[i]);
}

__global__ void catbias(const float* __restrict__ bq, const float* __restrict__ bk,
                        const float* __restrict__ bv, float* __restrict__ dst) {
  int i = blockIdx.x * 256 + threadIdx.x;
  if (i >= 3 * 1536) return;
  int layer = i / 1536, c = i - layer * 1536;
  float v = (c < 512) ? bq[layer * 512 + c]
          : (c < 1024) ? bk[layer * 512 + c - 512]
          : bv[layer * 512 + c - 1024];
  dst[i] = v;
}

__global__ void repack_dcw(const float* __restrict__ dcw, unsigned short* __restrict__ wt, int n) {
  int i = blockIdx.x * 256 + threadIdx.x;
  if (i >= n) return;
  int t = i % 3; int rest = i / 3; int c = rest % 512; int lo = rest / 512;
  wt[(size_t)lo * 1536 + t * 512 + c] = f2bf(dcw[i]);
}

// ---- 2-stage deterministic mean over L=512 rows (f32 input) ----
__global__ void mean_part(const float* __restrict__ xin, float* __restrict__ part, int nblkPerB) {
  int blk = blockIdx.x;
  int b = blk / nblkPerB, pc = blk - b * nblkPerB;
  int tid = threadIdx.x;
  float s0 = 0.0f, s1 = 0.0f;
  int l0 = pc * 32;
  for (int r = 0; r < 32; r++) {
    size_t base = ((size_t)(b * 512 + l0 + r)) << 9;
    s0 += xin[base + tid];
    s1 += xin[base + 256 + tid];
  }
  part[((size_t)blk << 9) + tid] = s0;
  part[((size_t)blk << 9) + 256 + tid] = s1;
}
__global__ void mean_fin(const float* __restrict__ part, float* __restrict__ out,
                         int nblkPerB, int nb) {
  int i = blockIdx.x * 256 + threadIdx.x;
  if (i >= nb * 512) return;
  int b = i >> 9, d = i & 511;
  float s = 0.0f;
  for (int c = 0; c < nblkPerB; c++) s += part[((size_t)(b * nblkPerB + c) << 9) + d];
  out[i] = s * (1.0f / 512.0f);
}

// ---------------- host ------------------------------------------------------
extern "C" void kernel_launch(void* const* d_in, const int* in_sizes, int n_in,
                              void* d_out, int out_size, void* d_ws, size_t ws_size,
                              hipStream_t stream)
{
  (void)in_sizes; (void)n_in; (void)out_size;
  const float* x_enc = (const float*)d_in[0];
  const float* emb_w = (const float*)d_in[1];
  const float* wq   = (const float*)d_in[2];
  const float* bq   = (const float*)d_in[3];
  const float* wk   = (const float*)d_in[4];
  const float* bk   = (const float*)d_in[5];
  const float* wv   = (const float*)d_in[6];
  const float* bvv  = (const float*)d_in[7];
  const float* wo   = (const float*)d_in[8];
  const float* bo   = (const float*)d_in[9];
  const float* c1w  = (const float*)d_in[10];
  const float* c1b  = (const float*)d_in[11];
  const float* c2w  = (const float*)d_in[12];
  const float* c2b  = (const float*)d_in[13];
  const float* ln1g = (const float*)d_in[14];
  const float* ln1b = (const float*)d_in[15];
  const float* ln2g = (const float*)d_in[16];
  const float* ln2b = (const float*)d_in[17];
  const float* dcw  = (const float*)d_in[18];
  const float* dcb  = (const float*)d_in[19];
  const float* bng  = (const float*)d_in[20];
  const float* bnb  = (const float*)d_in[21];
  const float* lnfg = (const float*)d_in[22];
  const float* lnfb = (const float*)d_in[23];

  // ---- choose batch-chunk size: need = 16MB + nb*8.8MB ----
  int nb = 32;
  while (nb > 1 && (16777216ull + (size_t)nb * 8804352ull) > ws_size) nb >>= 1;

  // ---- fixed small region (first 16MB) ----
  char* ws = (char*)d_ws;
  size_t off = 0;
  unsigned short* WQKV = (unsigned short*)(ws + off); off += 4718592ull;
  unsigned short* WOB  = (unsigned short*)(ws + off); off += 1572864ull;
  unsigned short* C1WB = (unsigned short*)(ws + off); off += 1572864ull;
  unsigned short* C2WB = (unsigned short*)(ws + off); off += 1572864ull;
  unsigned short* WTB  = (unsigned short*)(ws + off); off += 3145728ull;
  float* BQKVB         = (float*)(ws + off);          off += 18432ull;
  float* MP            = (float*)(ws + off);          off += 2097152ull;
  int* IDXP            = (int*)(ws + off);            off += 589824ull;
  int* MTOPP           = (int*)(ws + off);            off += 24576ull;

  // ---- chunk region ----
  size_t cb = 16777216ull;
  unsigned short* Xbf  = (unsigned short*)(ws + cb);
  char* R              = ws + cb + (size_t)nb * 2097152ull;
  unsigned short* DQ   = (unsigned short*)R;
  unsigned short* DK   = (unsigned short*)(R + (size_t)nb * 2097152ull);
  unsigned short* DV   = (unsigned short*)(R + (size_t)nb * 4194304ull);
  unsigned short* TMPB = DQ;                             // bf16 GEMM out (Q dead)
  float* TMPF          = (float*)DK;                     // final-LN f32 (K dead)
  unsigned short* AB   = DV;                             // ctx/ffn-mid (V dead)
  float* PUPD          = (float*)(ws + cb + (size_t)nb * 8388608ull);
  float* PDEN          = (float*)((char*)PUPD + (size_t)nb * 393216ull);
  float* PVS           = (float*)((char*)PDEN + (size_t)nb * 6144ull);
  const size_t qkvs    = (size_t)nb * 1048576ull;

  // ---- weights to bf16 (once) ----
  {
    int nw = 3 * 512 * 512;
    int blocks = (nw + 255) / 256;
    cvt_qkv<<<blocks, 256, 0, stream>>>(wq, WQKV, 0);
    cvt_qkv<<<blocks, 256, 0, stream>>>(wk, WQKV, 262144);
    cvt_qkv<<<blocks, 256, 0, stream>>>(wv, WQKV, 524288);
    catbias<<<18, 256, 0, stream>>>(bq, bk, bvv, BQKVB);
    cvt_kernel<<<blocks, 256, 0, stream>>>(wo,  WOB,  nw);
    cvt_kernel<<<blocks, 256, 0, stream>>>(c1w, C1WB, nw);
    cvt_kernel<<<blocks, 256, 0, stream>>>(c2w, C2WB, nw);
    int nd = 2 * 512 * 512 * 3;
    repack_dcw<<<(nd + 255) / 256, 256, 0, stream>>>(dcw, WTB, nd);
  }

  // ---- sample indices per layer (once) ----
  for (int layer = 0; layer < 3; layer++) {
    int Ll = (layer == 0) ? 2048 : (layer == 1 ? 1024 : 512);
    int ul = (layer == 0) ? 24 : 21;
    uint32_t f0, f1, a0, b0k, a1, b1k;
    tf2x32(0u, 42u, 0u, (uint32_t)layer, &f0, &f1);
    tf2x32(f0, f1, 0u, 2u, &a0, &b0k);
    tf2x32(f0, f1, 1u, 3u, &a1, &b1k);
    (void)a0; (void)a1;
    int nhalf = Ll * ul / 2;
    idx_kernel<<<(nhalf + 255) / 256, 256, 0, stream>>>(IDXP + layer * 49152, nhalf, b0k, b1k, Ll - 1);
  }

  // ---- per-chunk full pipeline ----
  for (int b0 = 0; b0 < 32; b0 += nb) {
    embed_kernel<<<nb * 64, 256, 0, stream>>>(x_enc + (size_t)b0 * 2048 * 7, emb_w, Xbf);

    int L = 2048, Lsh = 11;
    for (int layer = 0; layer < 3; layer++) {
      const int M_ = nb * L;
      const int u = (layer == 0) ? 24 : 21;
      const int S = L >> 8;
      const int nbm = M_ / 128;
      const int ng  = 4 * nbm;
      const int ngq = 12 * nbm;
      const int xsg  = (ng  % 8 == 0) ? 1 : 0;
      const int xsgq = (ngq % 8 == 0) ? 1 : 0;
      const int xg = (nb % 8 == 0) ? 1 : 0;

      gemm_bt<3,0><<<ngq, 256, 0, stream>>>(Xbf, WQKV + (size_t)layer * 786432, BQKVB + layer * 1536, DQ, M_, 1536, 512, 0, 0, qkvs, 12, xsgq);

      if (u == 24) msamp_kernel<24><<<nb * (L / 16), 256, 0, stream>>>(DQ, DK, IDXP + layer * 49152, MP, L, L / 16, 1.0f / (float)L, xg);
      else         msamp_kernel<21><<<nb * (L / 16), 256, 0, stream>>>(DQ, DK, IDXP + layer * 49152, MP, L, L / 16, 1.0f / (float)L, xg);

      if (L == 2048)      topk_kernel<8><<<nb * 8, 256, 0, stream>>>(MP, MTOPP, L, u);
      else if (L == 1024) topk_kernel<4><<<nb * 8, 256, 0, stream>>>(MP, MTOPP, L, u);
      else                topk_kernel<2><<<nb * 8, 256, 0, stream>>>(MP, MTOPP, L, u);

      if (u == 24) {
        attn_part<24><<<nb * 8 * S, 256, 0, stream>>>(DQ, DK, DV, MTOPP, PUPD, PDEN, PVS, L, S);
        attn_comb<24><<<nb * 8, 256, 0, stream>>>(MTOPP, PUPD, PDEN, PVS, AB, L, S);
      } else {
        attn_part<21><<<nb * 8 * S, 256, 0, stream>>>(DQ, DK, DV, MTOPP, PUPD, PDEN, PVS, L, S);
        attn_comb<21><<<nb * 8, 256, 0, stream>>>(MTOPP, PUPD, PDEN, PVS, AB, L, S);
      }

      // Q/K/V dead; TMPB (=DQ) live from here.
      gemm_bt<1,0><<<ng, 256, 0, stream>>>(AB, WOB + (size_t)layer * 262144, bo + layer * 512, TMPB, M_, 512, 512, 0, 0, 0, 4, xsg);
      ln_kernel<<<M_, 256, 0, stream>>>(TMPB, Xbf, ln1g + layer * 512, ln1b + layer * 512, Xbf, nullptr);
      gemm_bt<2,0><<<ng, 256, 0, stream>>>(Xbf, C1WB + (size_t)layer * 262144, c1b + layer * 512, AB, M_, 512, 512, 0, 0, 0, 4, xsg);
      gemm_bt<1,0><<<ng, 256, 0, stream>>>(AB, C2WB + (size_t)layer * 262144, c2b + layer * 512, TMPB, M_, 512, 512, 0, 0, 0, 4, xsg);
      ln_kernel<<<M_, 256, 0, stream>>>(TMPB, Xbf, ln2g + layer * 512, ln2b + layer * 512, Xbf, nullptr);

      if (layer < 2) {
        gemm_bt<1,1><<<ng, 256, 0, stream>>>(Xbf, WTB + (size_t)layer * 786432, dcb + layer * 512, TMPB, M_, 512, 1536, L, Lsh, 0, 4, xsg);
        pool_kernel<<<nb * (L / 2), 256, 0, stream>>>(TMPB, bng + layer * 512, bnb + layer * 512, Xbf, L, nb * (L / 2) * 256);
        L >>= 1; Lsh -= 1;
      }
    }

    ln_kernel<<<nb * 512, 256, 0, stream>>>(nullptr, Xbf, lnfg, lnfb, nullptr, TMPF);
    mean_part<<<nb * 16, 256, 0, stream>>>(TMPF, MP, 16);
    mean_fin<<<(nb * 512 + 255) / 256, 256, 0, stream>>>(MP, (float*)d_out + (size_t)b0 * 512, 16, nb);
  }
}